// Round 2
// baseline (6828.303 us; speedup 1.0000x reference)
//
#include <hip/hip_runtime.h>
#include <math.h>

#define NPOLES 80
#define NP 161          // 2*NPOLES+1
#define NPAD 164        // NP padded to multiple of 4
#define TSEQ 36
#define NSAMP 128
#define DDATA 50
#define LAMF 0.1f
#define NPD (NP*DDATA)      // 8050
#define TD (TSEQ*DDATA)     // 1800
#define CSIZE (NSAMP*NPD)   // 1030400
#define RSIZE (NSAMP*TD)    // 230400
#define DSIZE (TSEQ*NP)     // 5796

// ---------------- D matrix (clamped poles), f32 to ws + f32 to out ----------
__global__ void k_build_D(const float* __restrict__ rho, const float* __restrict__ theta,
                          float* __restrict__ Dw, float* __restrict__ Dout) {
    int idx = blockIdx.x * 256 + threadIdx.x;
    if (idx >= DSIZE) return;
    int t = idx / NP, p = idx - (idx / NP) * NP;
    float v;
    if (p == 0) {
        v = 1.f;
    } else {
        int j = (p <= NPOLES) ? (p - 1) : (p - 1 - NPOLES);
        float r  = fminf(fmaxf(rho[j],   0.8f), 1.1f);
        float th = fminf(fmaxf(theta[j], 0.1f), 3.14159265358979323846f);
        double pw  = pow((double)r, (double)t);
        double ang = (double)t * (double)th;
        v = (float)(pw * ((p <= NPOLES) ? cos(ang) : sin(ang)));
    }
    Dw[idx] = v;
    Dout[idx] = v;
}

// ---------------- DDt = D @ D^T  [36x36] (same nonzero eigvals as DtD) -------
__global__ void k_ddt(const float* __restrict__ Dw, float* __restrict__ DDt) {
    int idx = blockIdx.x * 256 + threadIdx.x;
    if (idx >= TSEQ * TSEQ) return;
    int i = idx / TSEQ, j = idx - (idx / TSEQ) * TSEQ;
    float acc = 0.f;
    for (int p = 0; p < NP; ++p) acc = fmaf(Dw[i * NP + p], Dw[j * NP + p], acc);
    DDt[idx] = acc;
}

// ---------------- power iteration on 36x36 -> L = lambda_max, scal[0]=1/L ----
__global__ void k_power(const float* __restrict__ DDt, float* __restrict__ scal) {
    __shared__ float sM[TSEQ * TSEQ];
    __shared__ float sv[TSEQ];
    int tid = threadIdx.x;  // 64 threads = 1 wave
    for (int i = tid; i < TSEQ * TSEQ; i += 64) sM[i] = DDt[i];
    if (tid < TSEQ) sv[tid] = 1.f;
    __syncthreads();
    for (int it = 0; it < 150; ++it) {
        float u = 0.f;
        if (tid < TSEQ) {
            for (int q = 0; q < TSEQ; ++q) u = fmaf(sM[tid * TSEQ + q], sv[q], u);
        }
        float nn = u * u;
        for (int o = 32; o > 0; o >>= 1) nn += __shfl_down(nn, o);
        nn = __shfl(nn, 0);
        float inv = rsqrtf(nn);
        __syncthreads();
        if (tid < TSEQ) sv[tid] = u * inv;
        __syncthreads();
    }
    float rq = 0.f;
    if (tid < TSEQ) {
        float uu = 0.f;
        for (int q = 0; q < TSEQ; ++q) uu = fmaf(sM[tid * TSEQ + q], sv[q], uu);
        rq = uu * sv[tid];
    }
    for (int o = 32; o > 0; o >>= 1) rq += __shfl_down(rq, o);
    if (tid == 0) { scal[0] = 1.f / rq; scal[1] = rq; }
}

// ---------------- A = I - DtD/L, stored padded+symmetric: Apad[q][p] ---------
__global__ void k_A(const float* __restrict__ Dw, const float* __restrict__ scal,
                    float* __restrict__ Apad) {
    int idx = blockIdx.x * 256 + threadIdx.x;
    if (idx >= NP * NPAD) return;
    int q = idx / NPAD, p = idx - (idx / NPAD) * NPAD;
    float v = 0.f;
    if (p < NP) {
        float acc = 0.f;
        for (int t = 0; t < TSEQ; ++t) acc = fmaf(Dw[t * NP + q], Dw[t * NP + p], acc);
        v = ((p == q) ? 1.f : 0.f) - acc * scal[0];
    }
    Apad[idx] = v;
}

// ---------------- DtY[n,p,d] = sum_t D[t,p] * Y[n,t,d] ----------------------
__global__ void k_dty(const float* __restrict__ Dw, const float* __restrict__ Y,
                      float* __restrict__ dty) {
    int idx = blockIdx.x * 256 + threadIdx.x;
    if (idx >= CSIZE) return;
    int n = idx / NPD;
    int r = idx - n * NPD;
    int p = r / DDATA;
    int d = r - p * DDATA;
    const float* yp = Y + n * TD + d;
    float acc = 0.f;
    for (int t = 0; t < TSEQ; ++t) acc = fmaf(Dw[t * NP + p], yp[t * DDATA], acc);
    dty[idx] = acc;
}

// ---------------- fused FISTA iteration -------------------------------------
__device__ __forceinline__ void epi4(float4 a, int p, int base, int dd0,
                                     const float* __restrict__ dty, const float* __restrict__ wf,
                                     float* __restrict__ xf, float* __restrict__ yout,
                                     float Linv, float tt, int use_w) {
    if (p >= NP) return;
    int rbase = base + p * DDATA + dd0;
    float av[4] = {a.x, a.y, a.z, a.w};
#pragma unroll
    for (int j = 0; j < 4; ++j) {
        if (dd0 + j < 25) {
            int idx = rbase + j;
            float dv = dty[idx];
            float wv = use_w ? wf[idx] : 1.f;
            float wl = wv * (LAMF * Linv);
            float b  = fmaf(dv, Linv, av[j]);
            float xn = fmaxf(b - wl, 0.f) + fminf(b + wl, 0.f);
            float xo = xf[idx];
            xf[idx]   = xn;
            yout[idx] = fmaf(tt, xn - xo, xn);
        }
    }
}

__global__ __launch_bounds__(256) void k_iter(
    const float* __restrict__ Apad, const float* __restrict__ yin,
    float* __restrict__ yout, float* __restrict__ xf,
    const float* __restrict__ dty, const float* __restrict__ wf,
    const float* __restrict__ scal, const int use_w, const float tt) {
    __shared__ float yl[NP][28];
    const int tid = threadIdx.x;
    const int n  = blockIdx.x >> 1;
    const int dh = blockIdx.x & 1;
    const float Linv = scal[0];
    const int base = n * NPD + dh * 25;

    for (int i = tid; i < NP * 28; i += 256) {
        int q = i / 28, dd = i - q * 28;
        yl[q][dd] = (dd < 25) ? yin[base + q * DDATA + dd] : 0.f;
    }
    __syncthreads();

    for (int tile = tid; tile < 41 * 7; tile += 256) {
        int pg = tile / 7, dg = tile - pg * 7;
        int p0 = pg * 4, dd0 = dg * 4;
        float4 a0 = {0, 0, 0, 0}, a1 = a0, a2 = a0, a3 = a0;
        const float* Ap = Apad + p0;
        for (int q = 0; q < NP; ++q) {
            float4 av = *reinterpret_cast<const float4*>(Ap + q * NPAD);
            float4 yv = *reinterpret_cast<const float4*>(&yl[q][dd0]);
            a0.x = fmaf(av.x, yv.x, a0.x); a0.y = fmaf(av.x, yv.y, a0.y);
            a0.z = fmaf(av.x, yv.z, a0.z); a0.w = fmaf(av.x, yv.w, a0.w);
            a1.x = fmaf(av.y, yv.x, a1.x); a1.y = fmaf(av.y, yv.y, a1.y);
            a1.z = fmaf(av.y, yv.z, a1.z); a1.w = fmaf(av.y, yv.w, a1.w);
            a2.x = fmaf(av.z, yv.x, a2.x); a2.y = fmaf(av.z, yv.y, a2.y);
            a2.z = fmaf(av.z, yv.z, a2.z); a2.w = fmaf(av.z, yv.w, a2.w);
            a3.x = fmaf(av.w, yv.x, a3.x); a3.y = fmaf(av.w, yv.y, a3.y);
            a3.z = fmaf(av.w, yv.z, a3.z); a3.w = fmaf(av.w, yv.w, a3.w);
        }
        epi4(a0, p0 + 0, base, dd0, dty, wf, xf, yout, Linv, tt, use_w);
        epi4(a1, p0 + 1, base, dd0, dty, wf, xf, yout, Linv, tt, use_w);
        epi4(a2, p0 + 2, base, dd0, dty, wf, xf, yout, Linv, tt, use_w);
        epi4(a3, p0 + 3, base, dd0, dty, wf, xf, yout, Linv, tt, use_w);
    }
}

// ---------------- reweighting: w = (1/(|C|+.01)) / sum_p(...) * NP ----------
__global__ void k_weights(const float* __restrict__ xf, float* __restrict__ wf) {
    int idx = blockIdx.x * 256 + threadIdx.x;
    if (idx >= NSAMP * DDATA) return;
    int n = idx / DDATA, d = idx - (idx / DDATA) * DDATA;
    int base = n * NPD + d;
    float s = 0.f;
    for (int p = 0; p < NP; ++p) s += 1.f / (fabsf(xf[base + p * DDATA]) + 0.01f);
    float scale = (float)NP / s;
    for (int p = 0; p < NP; ++p)
        wf[base + p * DDATA] = (1.f / (fabsf(xf[base + p * DDATA]) + 0.01f)) * scale;
}

// ---------------- output conversion / reconstruction ------------------------
__global__ void k_store_C(const float* __restrict__ xf, float* __restrict__ Cout) {
    int idx = blockIdx.x * 256 + threadIdx.x;
    if (idx < CSIZE) Cout[idx] = xf[idx];
}

__global__ void k_R(const float* __restrict__ Dw, const float* __restrict__ xf,
                    float* __restrict__ Rout) {
    int idx = blockIdx.x * 256 + threadIdx.x;
    if (idx >= RSIZE) return;
    int n = idx / TD;
    int r = idx - n * TD;
    int t = r / DDATA;
    int d = r - t * DDATA;
    const float* xp = xf + n * NPD + d;
    float acc = 0.f;
    for (int p = 0; p < NP; ++p) acc = fmaf(Dw[t * NP + p], xp[p * DDATA], acc);
    Rout[idx] = acc;
}

extern "C" void kernel_launch(void* const* d_in, const int* in_sizes, int n_in,
                              void* d_out, int out_size, void* d_ws, size_t ws_size,
                              hipStream_t stream) {
    const float* Y     = (const float*)d_in[0];
    const float* rho   = (const float*)d_in[1];
    const float* theta = (const float*)d_in[2];
    float* Cout = (float*)d_out;
    float* Dout = Cout + CSIZE;
    float* Rout = Dout + DSIZE;

    float* ws   = (float*)d_ws;
    float* Dw   = ws;               // 5824
    float* Apad = Dw + 5824;        // 26416
    float* DDt  = Apad + 26416;     // 1312
    float* scal = DDt + 1312;       // 16
    float* dty  = scal + 16;        // CSIZE
    float* xf   = dty + CSIZE;      // CSIZE (f32 FISTA state)
    float* ya   = xf + CSIZE;       // CSIZE
    float* yb   = ya + CSIZE;       // CSIZE
    float* wf   = yb + CSIZE;       // CSIZE

    k_build_D<<<(DSIZE + 255) / 256, 256, 0, stream>>>(rho, theta, Dw, Dout);
    k_ddt<<<(TSEQ * TSEQ + 255) / 256, 256, 0, stream>>>(Dw, DDt);
    k_power<<<1, 64, 0, stream>>>(DDt, scal);
    k_A<<<(NP * NPAD + 255) / 256, 256, 0, stream>>>(Dw, scal, Apad);
    k_dty<<<(CSIZE + 255) / 256, 256, 0, stream>>>(Dw, Y, dty);

    // FISTA momentum sequence is data-independent: precompute on host
    float ttv[100];
    {
        double t = 1.0;
        for (int k = 0; k < 100; ++k) {
            double tn = (1.0 + sqrt(1.0 + 4.0 * t * t)) * 0.5;
            ttv[k] = (float)((t - 1.0) / tn);
            t = tn;
        }
    }

    for (int round = 0; round < 2; ++round) {
        hipMemsetAsync(xf, 0, (size_t)CSIZE * 4, stream);
        hipMemsetAsync(ya, 0, (size_t)CSIZE * 4, stream);
        float* cur = ya;
        float* nxt = yb;
        for (int k = 0; k < 100; ++k) {
            k_iter<<<NSAMP * 2, 256, 0, stream>>>(Apad, cur, nxt, xf, dty, wf, scal, round, ttv[k]);
            float* tmp = cur; cur = nxt; nxt = tmp;
        }
        if (round == 0) k_weights<<<(NSAMP * DDATA + 255) / 256, 256, 0, stream>>>(xf, wf);
    }

    k_store_C<<<(CSIZE + 255) / 256, 256, 0, stream>>>(xf, Cout);
    k_R<<<(RSIZE + 255) / 256, 256, 0, stream>>>(Dw, xf, Rout);
}

// Round 3
// 3004.825 us; speedup vs baseline: 2.2724x; 2.2724x over previous
//
#include <hip/hip_runtime.h>
#include <math.h>

#define NPOLES 80
#define NP 161          // 2*NPOLES+1
#define NPAD 164        // NP padded for float4 rows
#define YPAD 28
#define TSEQ 36
#define NSAMP 128
#define DDATA 50
#define LAMF 0.1f
#define NPD (NP*DDATA)      // 8050
#define TD (TSEQ*DDATA)     // 1800
#define CSIZE (NSAMP*NPD)   // 1030400
#define RSIZE (NSAMP*TD)    // 230400
#define DSIZE (TSEQ*NP)     // 5796

// ---------------- D matrix (clamped poles) ----------------------------------
__global__ void k_build_D(const float* __restrict__ rho, const float* __restrict__ theta,
                          float* __restrict__ Dw, float* __restrict__ Dout) {
    int idx = blockIdx.x * 256 + threadIdx.x;
    if (idx >= DSIZE) return;
    int t = idx / NP, p = idx - (idx / NP) * NP;
    float v;
    if (p == 0) {
        v = 1.f;
    } else {
        int j = (p <= NPOLES) ? (p - 1) : (p - 1 - NPOLES);
        float r  = fminf(fmaxf(rho[j],   0.8f), 1.1f);
        float th = fminf(fmaxf(theta[j], 0.1f), 3.14159265358979323846f);
        double pw  = pow((double)r, (double)t);
        double ang = (double)t * (double)th;
        v = (float)(pw * ((p <= NPOLES) ? cos(ang) : sin(ang)));
    }
    Dw[idx] = v;
    Dout[idx] = v;
}

// ---------------- DDt = D @ D^T  [36x36] ------------------------------------
__global__ void k_ddt(const float* __restrict__ Dw, float* __restrict__ DDt) {
    int idx = blockIdx.x * 256 + threadIdx.x;
    if (idx >= TSEQ * TSEQ) return;
    int i = idx / TSEQ, j = idx - (idx / TSEQ) * TSEQ;
    float acc = 0.f;
    for (int p = 0; p < NP; ++p) acc = fmaf(Dw[i * NP + p], Dw[j * NP + p], acc);
    DDt[idx] = acc;
}

// ---------------- power iteration -> scal[0]=1/L ----------------------------
__global__ void k_power(const float* __restrict__ DDt, float* __restrict__ scal) {
    __shared__ float sM[TSEQ * TSEQ];
    __shared__ float sv[TSEQ];
    int tid = threadIdx.x;  // 64 threads = 1 wave
    for (int i = tid; i < TSEQ * TSEQ; i += 64) sM[i] = DDt[i];
    if (tid < TSEQ) sv[tid] = 1.f;
    __syncthreads();
    for (int it = 0; it < 150; ++it) {
        float u = 0.f;
        if (tid < TSEQ) {
            for (int q = 0; q < TSEQ; ++q) u = fmaf(sM[tid * TSEQ + q], sv[q], u);
        }
        float nn = u * u;
        for (int o = 32; o > 0; o >>= 1) nn += __shfl_down(nn, o);
        nn = __shfl(nn, 0);
        float inv = rsqrtf(nn);
        __syncthreads();
        if (tid < TSEQ) sv[tid] = u * inv;
        __syncthreads();
    }
    float rq = 0.f;
    if (tid < TSEQ) {
        float uu = 0.f;
        for (int q = 0; q < TSEQ; ++q) uu = fmaf(sM[tid * TSEQ + q], sv[q], uu);
        rq = uu * sv[tid];
    }
    for (int o = 32; o > 0; o >>= 1) rq += __shfl_down(rq, o);
    if (tid == 0) { scal[0] = 1.f / rq; scal[1] = rq; }
}

// ---------------- A = I - DtD/L, padded symmetric [q][p] --------------------
__global__ void k_A(const float* __restrict__ Dw, const float* __restrict__ scal,
                    float* __restrict__ Apad) {
    int idx = blockIdx.x * 256 + threadIdx.x;
    if (idx >= NP * NPAD) return;
    int q = idx / NPAD, p = idx - (idx / NPAD) * NPAD;
    float v = 0.f;
    if (p < NP) {
        float acc = 0.f;
        for (int t = 0; t < TSEQ; ++t) acc = fmaf(Dw[t * NP + q], Dw[t * NP + p], acc);
        v = ((p == q) ? 1.f : 0.f) - acc * scal[0];
    }
    Apad[idx] = v;
}

// ---------------- DtY[n,p,d] = sum_t D[t,p] * Y[n,t,d] ----------------------
__global__ void k_dty(const float* __restrict__ Dw, const float* __restrict__ Y,
                      float* __restrict__ dty) {
    int idx = blockIdx.x * 256 + threadIdx.x;
    if (idx >= CSIZE) return;
    int n = idx / NPD;
    int r = idx - n * NPD;
    int p = r / DDATA;
    int d = r - p * DDATA;
    const float* yp = Y + n * TD + d;
    float acc = 0.f;
    for (int t = 0; t < TSEQ; ++t) acc = fmaf(Dw[t * NP + p], yp[t * DDATA], acc);
    dty[idx] = acc;
}

// ---------------- persistent FISTA: both rounds, 100 iters each -------------
// block = (n, d-half of 25 cols). Tiles: 40 p-groups (39x4 rows + 1x5 rows)
// x 25 cols = 1000 tiles over 256 threads (4 per thread, last pass 232 act.)
__global__ __launch_bounds__(256) void k_fista(
    const float* __restrict__ Apad, const float* __restrict__ dty_g,
    const float* __restrict__ scal, float* __restrict__ Cout)
{
    __shared__ __align__(16) float sA[NP][NPAD];   // 105616 B
    __shared__ float sY[NP][YPAD];                 //  18032 B
    __shared__ float sS[32];
    const int tid = threadIdx.x;
    const int n   = blockIdx.x >> 1;
    const int dh  = blockIdx.x & 1;
    const float Linv = scal[0];
    const float lamL = LAMF * Linv;

    int p0[4], dc[4]; bool val[4], fv[4];
#pragma unroll
    for (int s = 0; s < 4; ++s) {
        int t = s * 256 + tid;
        val[s] = (t < 1000);
        int tc = val[s] ? t : 0;
        int pg = tc / 25;
        dc[s] = tc - pg * 25;
        p0[s] = pg * 4;
        fv[s] = (pg == 39);      // 5-row tile (rows 156..160)
    }

    // load dty into registers
    float dt[4][5];
#pragma unroll
    for (int s = 0; s < 4; ++s) {
        int gbase = n * NPD + p0[s] * DDATA + dh * 25 + dc[s];
#pragma unroll
        for (int j = 0; j < 5; ++j) {
            bool ok = val[s] && (j < 4 || fv[s]);
            dt[s][j] = ok ? dty_g[gbase + j * DDATA] : 0.f;
        }
    }

    // stage A into LDS (26404 floats = 6601 float4)
    {
        const float4* src = (const float4*)Apad;
        float4* dst = (float4*)&sA[0][0];
        for (int i = tid; i < (NP * NPAD) / 4; i += 256) dst[i] = src[i];
    }

    float x[4][5], w[4][5], yn[4][5];
#pragma unroll
    for (int s = 0; s < 4; ++s)
#pragma unroll
        for (int j = 0; j < 5; ++j) w[s][j] = 1.f;

#pragma unroll 1
    for (int round = 0; round < 2; ++round) {
#pragma unroll
        for (int s = 0; s < 4; ++s)
#pragma unroll
            for (int j = 0; j < 5; ++j) x[s][j] = 0.f;
        for (int i = tid; i < NP * YPAD; i += 256) (&sY[0][0])[i] = 0.f;
        float tmom = 1.f;
        __syncthreads();

#pragma unroll 1
        for (int it = 0; it < 100; ++it) {
            float tn = (1.f + sqrtf(fmaf(4.f * tmom, tmom, 1.f))) * 0.5f;
            float ttc = (tmom - 1.f) / tn;
            tmom = tn;

            float a00=0,a01=0,a02=0,a03=0;
            float a10=0,a11=0,a12=0,a13=0;
            float a20=0,a21=0,a22=0,a23=0;
            float a30=0,a31=0,a32=0,a33=0,a34=0;
            {
                const float* A0 = &sA[0][p0[0]];
                const float* A1 = &sA[0][p0[1]];
                const float* A2 = &sA[0][p0[2]];
                const float* A3 = &sA[0][p0[3]];
                const float* Y0 = &sY[0][dc[0]];
                const float* Y1 = &sY[0][dc[1]];
                const float* Y2 = &sY[0][dc[2]];
                const float* Y3 = &sY[0][dc[3]];
#pragma unroll 2
                for (int q = 0; q < NP; ++q) {
                    float4 v0 = *(const float4*)A0;
                    float4 v1 = *(const float4*)A1;
                    float4 v2 = *(const float4*)A2;
                    float4 v3 = *(const float4*)A3;
                    float e3 = A3[4];                  // 5th row (used iff fv[3])
                    float y0 = *Y0, y1 = *Y1, y2 = *Y2, y3 = *Y3;
                    a00 = fmaf(v0.x, y0, a00); a01 = fmaf(v0.y, y0, a01);
                    a02 = fmaf(v0.z, y0, a02); a03 = fmaf(v0.w, y0, a03);
                    a10 = fmaf(v1.x, y1, a10); a11 = fmaf(v1.y, y1, a11);
                    a12 = fmaf(v1.z, y1, a12); a13 = fmaf(v1.w, y1, a13);
                    a20 = fmaf(v2.x, y2, a20); a21 = fmaf(v2.y, y2, a21);
                    a22 = fmaf(v2.z, y2, a22); a23 = fmaf(v2.w, y2, a23);
                    a30 = fmaf(v3.x, y3, a30); a31 = fmaf(v3.y, y3, a31);
                    a32 = fmaf(v3.z, y3, a32); a33 = fmaf(v3.w, y3, a33);
                    a34 = fmaf(e3,   y3, a34);
                    A0 += NPAD; A1 += NPAD; A2 += NPAD; A3 += NPAD;
                    Y0 += YPAD; Y1 += YPAD; Y2 += YPAD; Y3 += YPAD;
                }
            }

#define EPI(s, j, accv) { \
    float bb = fmaf(dt[s][j], Linv, (accv)); \
    float wl = w[s][j] * lamL; \
    float xn = fmaxf(bb - wl, 0.f) + fminf(bb + wl, 0.f); \
    float xo = x[s][j]; \
    x[s][j] = xn; \
    yn[s][j] = fmaf(ttc, xn - xo, xn); \
}
            EPI(0,0,a00) EPI(0,1,a01) EPI(0,2,a02) EPI(0,3,a03)
            EPI(1,0,a10) EPI(1,1,a11) EPI(1,2,a12) EPI(1,3,a13)
            EPI(2,0,a20) EPI(2,1,a21) EPI(2,2,a22) EPI(2,3,a23)
            EPI(3,0,a30) EPI(3,1,a31) EPI(3,2,a32) EPI(3,3,a33) EPI(3,4,a34)
#undef EPI

            __syncthreads();
#pragma unroll
            for (int s = 0; s < 4; ++s) {
#pragma unroll
                for (int j = 0; j < 5; ++j) {
                    if ((j < 4 || fv[s]) && val[s])
                        sY[p0[s] + j][dc[s]] = yn[s][j];
                }
            }
            __syncthreads();
        }

        if (round == 0) {
            // in-block reweighting: w = winv / colsum(winv) * NP
#pragma unroll
            for (int s = 0; s < 4; ++s)
#pragma unroll
                for (int j = 0; j < 5; ++j)
                    if ((j < 4 || fv[s]) && val[s])
                        sY[p0[s] + j][dc[s]] = 1.f / (fabsf(x[s][j]) + 0.01f);
            __syncthreads();
            if (tid < 25) {
                float ssum = 0.f;
                for (int q = 0; q < NP; ++q) ssum += sY[q][tid];
                sS[tid] = (float)NP / ssum;
            }
            __syncthreads();
#pragma unroll
            for (int s = 0; s < 4; ++s) {
                float sc = sS[dc[s]];
#pragma unroll
                for (int j = 0; j < 5; ++j)
                    w[s][j] = (1.f / (fabsf(x[s][j]) + 0.01f)) * sc;
            }
            __syncthreads();
        } else {
#pragma unroll
            for (int s = 0; s < 4; ++s)
#pragma unroll
                for (int j = 0; j < 5; ++j)
                    if ((j < 4 || fv[s]) && val[s])
                        Cout[n * NPD + (p0[s] + j) * DDATA + dh * 25 + dc[s]] = x[s][j];
        }
    }
}

// ---------------- R = D @ C (reads Cout) ------------------------------------
__global__ void k_R(const float* __restrict__ Dw, const float* __restrict__ Cf,
                    float* __restrict__ Rout) {
    int idx = blockIdx.x * 256 + threadIdx.x;
    if (idx >= RSIZE) return;
    int n = idx / TD;
    int r = idx - n * TD;
    int t = r / DDATA;
    int d = r - t * DDATA;
    const float* xp = Cf + n * NPD + d;
    float acc = 0.f;
    for (int p = 0; p < NP; ++p) acc = fmaf(Dw[t * NP + p], xp[p * DDATA], acc);
    Rout[idx] = acc;
}

extern "C" void kernel_launch(void* const* d_in, const int* in_sizes, int n_in,
                              void* d_out, int out_size, void* d_ws, size_t ws_size,
                              hipStream_t stream) {
    const float* Y     = (const float*)d_in[0];
    const float* rho   = (const float*)d_in[1];
    const float* theta = (const float*)d_in[2];
    float* Cout = (float*)d_out;
    float* Dout = Cout + CSIZE;
    float* Rout = Dout + DSIZE;

    float* ws   = (float*)d_ws;
    float* Dw   = ws;               // 5824
    float* Apad = Dw + 5824;        // 26416
    float* DDt  = Apad + 26416;     // 1312
    float* scal = DDt + 1312;       // 16
    float* dty  = scal + 16;        // CSIZE

    k_build_D<<<(DSIZE + 255) / 256, 256, 0, stream>>>(rho, theta, Dw, Dout);
    k_ddt<<<(TSEQ * TSEQ + 255) / 256, 256, 0, stream>>>(Dw, DDt);
    k_power<<<1, 64, 0, stream>>>(DDt, scal);
    k_A<<<(NP * NPAD + 255) / 256, 256, 0, stream>>>(Dw, scal, Apad);
    k_dty<<<(CSIZE + 255) / 256, 256, 0, stream>>>(Dw, Y, dty);

    k_fista<<<NSAMP * 2, 256, 0, stream>>>(Apad, dty, scal, Cout);

    k_R<<<(RSIZE + 255) / 256, 256, 0, stream>>>(Dw, Cout, Rout);
}

// Round 4
// 890.551 us; speedup vs baseline: 7.6675x; 3.3741x over previous
//
#include <hip/hip_runtime.h>
#include <math.h>

#define NPOLES 80
#define NP 161          // 2*NPOLES+1
#define NPAD 164
#define TSEQ 36
#define NSAMP 128
#define DDATA 50
#define LAMF 0.1f
#define NPD (NP*DDATA)      // 8050
#define TD (TSEQ*DDATA)     // 1800
#define CSIZE (NSAMP*NPD)   // 1030400
#define RSIZE (NSAMP*TD)    // 230400
#define DSIZE (TSEQ*NP)     // 5796

#define RT_N 11             // 176 padded rows / 16
#define KC_N 5              // k chunks of 32 (q=0..159); q=160 via rank-1
#define FRAG_CHUNK 512      // shorts per (rt,kc) fragment chunk: 64 lanes * 8
#define YK 168              // padded k-dim of transposed Y (stride 336B)

typedef __attribute__((ext_vector_type(8))) short s8b;
typedef __attribute__((ext_vector_type(4))) float f4;

__device__ __forceinline__ unsigned short f2b(float f) {
    unsigned u = __float_as_uint(f);
    unsigned r = (u + 0x7FFFu + ((u >> 16) & 1u)) >> 16;   // RNE to bf16
    return (unsigned short)r;
}
__device__ __forceinline__ float b2f(unsigned short h) {
    return __uint_as_float(((unsigned)h) << 16);
}

// ---------------- D matrix (clamped poles) ----------------------------------
__global__ void k_build_D(const float* __restrict__ rho, const float* __restrict__ theta,
                          float* __restrict__ Dw, float* __restrict__ Dout) {
    int idx = blockIdx.x * 256 + threadIdx.x;
    if (idx >= DSIZE) return;
    int t = idx / NP, p = idx - (idx / NP) * NP;
    float v;
    if (p == 0) {
        v = 1.f;
    } else {
        int j = (p <= NPOLES) ? (p - 1) : (p - 1 - NPOLES);
        float r  = fminf(fmaxf(rho[j],   0.8f), 1.1f);
        float th = fminf(fmaxf(theta[j], 0.1f), 3.14159265358979323846f);
        double pw  = pow((double)r, (double)t);
        double ang = (double)t * (double)th;
        v = (float)(pw * ((p <= NPOLES) ? cos(ang) : sin(ang)));
    }
    Dw[idx] = v;
    Dout[idx] = v;
}

// ---------------- DDt = D @ D^T  [36x36] ------------------------------------
__global__ void k_ddt(const float* __restrict__ Dw, float* __restrict__ DDt) {
    int idx = blockIdx.x * 256 + threadIdx.x;
    if (idx >= TSEQ * TSEQ) return;
    int i = idx / TSEQ, j = idx - (idx / TSEQ) * TSEQ;
    float acc = 0.f;
    for (int p = 0; p < NP; ++p) acc = fmaf(Dw[i * NP + p], Dw[j * NP + p], acc);
    DDt[idx] = acc;
}

// ---------------- power iteration -> scal[0]=1/L ----------------------------
__global__ void k_power(const float* __restrict__ DDt, float* __restrict__ scal) {
    __shared__ float sM[TSEQ * TSEQ];
    __shared__ float sv[TSEQ];
    int tid = threadIdx.x;  // 64 threads = 1 wave
    for (int i = tid; i < TSEQ * TSEQ; i += 64) sM[i] = DDt[i];
    if (tid < TSEQ) sv[tid] = 1.f;
    __syncthreads();
    for (int it = 0; it < 150; ++it) {
        float u = 0.f;
        if (tid < TSEQ) {
            for (int q = 0; q < TSEQ; ++q) u = fmaf(sM[tid * TSEQ + q], sv[q], u);
        }
        float nn = u * u;
        for (int o = 32; o > 0; o >>= 1) nn += __shfl_down(nn, o);
        nn = __shfl(nn, 0);
        float inv = rsqrtf(nn);
        __syncthreads();
        if (tid < TSEQ) sv[tid] = u * inv;
        __syncthreads();
    }
    float rq = 0.f;
    if (tid < TSEQ) {
        float uu = 0.f;
        for (int q = 0; q < TSEQ; ++q) uu = fmaf(sM[tid * TSEQ + q], sv[q], uu);
        rq = uu * sv[tid];
    }
    for (int o = 32; o > 0; o >>= 1) rq += __shfl_down(rq, o);
    if (tid == 0) { scal[0] = 1.f / rq; scal[1] = rq; }
}

// ---------------- A = I - DtD/L, padded symmetric [q][p] --------------------
__global__ void k_A(const float* __restrict__ Dw, const float* __restrict__ scal,
                    float* __restrict__ Apad) {
    int idx = blockIdx.x * 256 + threadIdx.x;
    if (idx >= NP * NPAD) return;
    int q = idx / NPAD, p = idx - (idx / NPAD) * NPAD;
    float v = 0.f;
    if (p < NP) {
        float acc = 0.f;
        for (int t = 0; t < TSEQ; ++t) acc = fmaf(Dw[t * NP + q], Dw[t * NP + p], acc);
        v = ((p == q) ? 1.f : 0.f) - acc * scal[0];
    }
    Apad[idx] = v;
}

// ---------------- DtY[n,p,d] = sum_t D[t,p] * Y[n,t,d] ----------------------
__global__ void k_dty(const float* __restrict__ Dw, const float* __restrict__ Y,
                      float* __restrict__ dty) {
    int idx = blockIdx.x * 256 + threadIdx.x;
    if (idx >= CSIZE) return;
    int n = idx / NPD;
    int r = idx - n * NPD;
    int p = r / DDATA;
    int d = r - p * DDATA;
    const float* yp = Y + n * TD + d;
    float acc = 0.f;
    for (int t = 0; t < TSEQ; ++t) acc = fmaf(Dw[t * NP + p], yp[t * DDATA], acc);
    dty[idx] = acc;
}

// ---------------- pack A into MFMA fragment order, split bf16 hi/lo ---------
// A-operand frag for mfma_f32_16x16x32_bf16: lane l holds row=(l&15),
// k = (l>>4)*8 + j (j=0..7). Chunk (rt,kc) stored contiguous: lane*8 shorts.
__global__ void k_Afrag(const float* __restrict__ Apad,
                        short* __restrict__ AfH, short* __restrict__ AfL) {
    int idx = blockIdx.x * 256 + threadIdx.x;
    if (idx >= RT_N * KC_N * 64) return;
    int lane = idx & 63;
    int chunk = idx >> 6;
    int kc = chunk % KC_N;
    int rt = chunk / KC_N;
    int p = rt * 16 + (lane & 15);
    int q0 = kc * 32 + (lane >> 4) * 8;
    int base = chunk * FRAG_CHUNK + lane * 8;
#pragma unroll
    for (int j = 0; j < 8; ++j) {
        int q = q0 + j;
        float v = (p < NP && q < NP) ? Apad[q * NPAD + p] : 0.f;  // A[p][q] (symmetric)
        unsigned short h = f2b(v);
        float rem = v - b2f(h);
        AfH[base + j] = (short)h;
        AfL[base + j] = (short)f2b(rem);
    }
}

// ---------------- persistent MFMA FISTA: both rounds, 100 iters each --------
// block=(n, d-half). 4 waves: wave w owns row-tiles rt0=w*3.. (3,3,3,2),
// both col-tiles. A-fragments streamed from global (L2-resident).
__global__ __launch_bounds__(256, 1) void k_fista(
    const float* __restrict__ Apad,
    const s8b* __restrict__ AfH, const s8b* __restrict__ AfL,
    const float* __restrict__ dty_g, const float* __restrict__ scal,
    float* __restrict__ Cout)
{
    __shared__ unsigned short Yh[32][YK];   // y transposed [col][k], bf16 hi
    __shared__ unsigned short Yl[32][YK];   // bf16 lo
    __shared__ float A160[176];             // A[:,160] f32
    __shared__ float yrem[32];              // y[160][col] f32
    __shared__ float colpart[4][2][16];
    __shared__ float sS[32];

    const int tid = threadIdx.x;
    const int n = blockIdx.x >> 1;
    const int dh = blockIdx.x & 1;
    const int w = tid >> 6;
    const int lane = tid & 63;
    const int c0 = lane & 15;
    const int g = lane >> 4;
    const int rt0 = w * 3;
    const int ntr = (w == 3) ? 2 : 3;
    const float Linv = scal[0];
    const float lamL = LAMF * Linv;

    for (int i = tid; i < 176; i += 256)
        A160[i] = (i < NP) ? Apad[160 * NPAD + i] : 0.f;

    // per-thread tile geometry + dty fragments (C/D layout: col=l&15, row=g*4+reg)
    float dt[6][4];
    bool vld[6];
    int rowb[6], colv[6];
#pragma unroll
    for (int i = 0; i < 6; ++i) {
        int rt = rt0 + (i >> 1);
        int ct = i & 1;
        vld[i] = (i >> 1) < ntr;
        rowb[i] = rt * 16 + g * 4;
        colv[i] = ct * 16 + c0;
#pragma unroll
        for (int r = 0; r < 4; ++r) {
            int row = rowb[i] + r;
            float v = 0.f;
            if (vld[i] && row < NP && colv[i] < 25)
                v = dty_g[n * NPD + row * DDATA + dh * 25 + colv[i]];
            dt[i][r] = v;
        }
    }

    float x_[6][4], w_[6][4];
#pragma unroll
    for (int i = 0; i < 6; ++i)
#pragma unroll
        for (int r = 0; r < 4; ++r) w_[i][r] = 1.f;

#pragma unroll 1
    for (int round = 0; round < 2; ++round) {
#pragma unroll
        for (int i = 0; i < 6; ++i)
#pragma unroll
            for (int r = 0; r < 4; ++r) x_[i][r] = 0.f;
        {   // zero y state
            unsigned* ph = (unsigned*)&Yh[0][0];
            unsigned* pl = (unsigned*)&Yl[0][0];
            for (int i = tid; i < 32 * YK / 2; i += 256) { ph[i] = 0u; pl[i] = 0u; }
            if (tid < 32) yrem[tid] = 0.f;
        }
        float tmom = 1.f;
        __syncthreads();

#pragma unroll 1
        for (int it = 0; it < 100; ++it) {
            float tn = (1.f + sqrtf(fmaf(4.f * tmom, tmom, 1.f))) * 0.5f;
            float ttc = (tmom - 1.f) / tn;
            tmom = tn;

            f4 acc[6];
#pragma unroll
            for (int i = 0; i < 6; ++i) acc[i] = (f4){0.f, 0.f, 0.f, 0.f};

#pragma unroll
            for (int kc = 0; kc < KC_N; ++kc) {
                int yo = kc * 32 + g * 8;
                s8b bh0 = *(const s8b*)&Yh[c0][yo];
                s8b bl0 = *(const s8b*)&Yl[c0][yo];
                s8b bh1 = *(const s8b*)&Yh[16 + c0][yo];
                s8b bl1 = *(const s8b*)&Yl[16 + c0][yo];
#pragma unroll
                for (int i = 0; i < 6; ++i) {
                    if ((i >> 1) < ntr) {
                        int rt = rt0 + (i >> 1);
                        s8b ah = AfH[(rt * KC_N + kc) * 64 + lane];
                        s8b al = AfL[(rt * KC_N + kc) * 64 + lane];
                        s8b bh = (i & 1) ? bh1 : bh0;
                        s8b bl = (i & 1) ? bl1 : bl0;
                        acc[i] = __builtin_amdgcn_mfma_f32_16x16x32_bf16(ah, bh, acc[i], 0, 0, 0);
                        acc[i] = __builtin_amdgcn_mfma_f32_16x16x32_bf16(ah, bl, acc[i], 0, 0, 0);
                        acc[i] = __builtin_amdgcn_mfma_f32_16x16x32_bf16(al, bh, acc[i], 0, 0, 0);
                    }
                }
            }
            {   // q=160 rank-1 term in f32
                float y0 = yrem[c0];
                float y1 = yrem[16 + c0];
#pragma unroll
                for (int i = 0; i < 6; ++i) {
                    if ((i >> 1) < ntr) {
                        const f4 a4 = *(const f4*)&A160[rowb[i]];
                        float yv = (i & 1) ? y1 : y0;
                        acc[i] += a4 * yv;
                    }
                }
            }
            __syncthreads();   // all reads of y-state done

            // epilogue: soft-threshold + momentum + write y (bf16 split, transposed)
#pragma unroll
            for (int i = 0; i < 6; ++i) {
                if ((i >> 1) < ntr) {
                    unsigned short hh[4], ll[4];
                    float yn0 = 0.f;
#pragma unroll
                    for (int r = 0; r < 4; ++r) {
                        float bb = fmaf(dt[i][r], Linv, acc[i][r]);
                        float wl = w_[i][r] * lamL;
                        float xn = fmaxf(bb - wl, 0.f) + fminf(bb + wl, 0.f);
                        float yn = fmaf(ttc, xn - x_[i][r], xn);
                        x_[i][r] = xn;
                        if (r == 0) yn0 = yn;
                        unsigned short h = f2b(yn);
                        hh[r] = h;
                        ll[r] = f2b(yn - b2f(h));
                    }
                    int rt = rt0 + (i >> 1);
                    if (rt < 10) {
                        uint2 hp, lp;
                        hp.x = (unsigned)hh[0] | ((unsigned)hh[1] << 16);
                        hp.y = (unsigned)hh[2] | ((unsigned)hh[3] << 16);
                        lp.x = (unsigned)ll[0] | ((unsigned)ll[1] << 16);
                        lp.y = (unsigned)ll[2] | ((unsigned)ll[3] << 16);
                        *(uint2*)&Yh[colv[i]][rowb[i]] = hp;
                        *(uint2*)&Yl[colv[i]][rowb[i]] = lp;
                    } else if (g == 0) {
                        yrem[colv[i]] = yn0;   // row 160 (rows >160 are pad, y=0)
                    }
                }
            }
            __syncthreads();   // y-state ready for next iter
        }

        if (round == 0) {
            // reweight: w = winv / colsum(winv) * NP  (colsum over p, rows<161)
            float ps0 = 0.f, ps1 = 0.f;
#pragma unroll
            for (int i = 0; i < 6; ++i) {
                if ((i >> 1) < ntr) {
#pragma unroll
                    for (int r = 0; r < 4; ++r) {
                        if (rowb[i] + r < NP) {
                            float wi = 1.f / (fabsf(x_[i][r]) + 0.01f);
                            if (i & 1) ps1 += wi; else ps0 += wi;
                        }
                    }
                }
            }
            ps0 += __shfl_xor(ps0, 16); ps0 += __shfl_xor(ps0, 32);
            ps1 += __shfl_xor(ps1, 16); ps1 += __shfl_xor(ps1, 32);
            if (lane < 16) { colpart[w][0][lane] = ps0; colpart[w][1][lane] = ps1; }
            __syncthreads();
            if (tid < 32) {
                int ct = tid >> 4, cc = tid & 15;
                float s = colpart[0][ct][cc] + colpart[1][ct][cc]
                        + colpart[2][ct][cc] + colpart[3][ct][cc];
                sS[tid] = (float)NP / s;
            }
            __syncthreads();
#pragma unroll
            for (int i = 0; i < 6; ++i) {
                float sc = sS[colv[i]];
#pragma unroll
                for (int r = 0; r < 4; ++r)
                    w_[i][r] = (1.f / (fabsf(x_[i][r]) + 0.01f)) * sc;
            }
            __syncthreads();
        }
    }

    // store C (f32)
#pragma unroll
    for (int i = 0; i < 6; ++i) {
        if (((i >> 1) < ntr) && colv[i] < 25) {
#pragma unroll
            for (int r = 0; r < 4; ++r) {
                int row = rowb[i] + r;
                if (row < NP)
                    Cout[n * NPD + row * DDATA + dh * 25 + colv[i]] = x_[i][r];
            }
        }
    }
}

// ---------------- R = D @ C ------------------------------------------------
__global__ void k_R(const float* __restrict__ Dw, const float* __restrict__ Cf,
                    float* __restrict__ Rout) {
    int idx = blockIdx.x * 256 + threadIdx.x;
    if (idx >= RSIZE) return;
    int n = idx / TD;
    int r = idx - n * TD;
    int t = r / DDATA;
    int d = r - t * DDATA;
    const float* xp = Cf + n * NPD + d;
    float acc = 0.f;
    for (int p = 0; p < NP; ++p) acc = fmaf(Dw[t * NP + p], xp[p * DDATA], acc);
    Rout[idx] = acc;
}

extern "C" void kernel_launch(void* const* d_in, const int* in_sizes, int n_in,
                              void* d_out, int out_size, void* d_ws, size_t ws_size,
                              hipStream_t stream) {
    const float* Y     = (const float*)d_in[0];
    const float* rho   = (const float*)d_in[1];
    const float* theta = (const float*)d_in[2];
    float* Cout = (float*)d_out;
    float* Dout = Cout + CSIZE;
    float* Rout = Dout + DSIZE;

    float* ws    = (float*)d_ws;
    float* Dw    = ws;                 // 5824
    float* Apad  = Dw + 5824;          // 26416
    float* DDt   = Apad + 26416;       // 1312
    float* scal  = DDt + 1312;         // 16
    float* dty   = scal + 16;          // CSIZE
    float* AfH_f = dty + CSIZE;        // 14080 floats (= 28160 shorts)
    float* AfL_f = AfH_f + 14080;      // 14080 floats

    k_build_D<<<(DSIZE + 255) / 256, 256, 0, stream>>>(rho, theta, Dw, Dout);
    k_ddt<<<(TSEQ * TSEQ + 255) / 256, 256, 0, stream>>>(Dw, DDt);
    k_power<<<1, 64, 0, stream>>>(DDt, scal);
    k_A<<<(NP * NPAD + 255) / 256, 256, 0, stream>>>(Dw, scal, Apad);
    k_dty<<<(CSIZE + 255) / 256, 256, 0, stream>>>(Dw, Y, dty);
    k_Afrag<<<(RT_N * KC_N * 64 + 255) / 256, 256, 0, stream>>>(Apad, (short*)AfH_f, (short*)AfL_f);

    k_fista<<<NSAMP * 2, 256, 0, stream>>>(Apad, (const s8b*)AfH_f, (const s8b*)AfL_f,
                                           dty, scal, Cout);

    k_R<<<(RSIZE + 255) / 256, 256, 0, stream>>>(Dw, Cout, Rout);
}

// Round 5
// 632.170 us; speedup vs baseline: 10.8014x; 1.4087x over previous
//
#include <hip/hip_runtime.h>
#include <math.h>

#define NPOLES 80
#define NP 161          // 2*NPOLES+1
#define NPAD 164
#define TSEQ 36
#define NSAMP 128
#define DDATA 50
#define LAMF 0.1f
#define NPD (NP*DDATA)      // 8050
#define TD (TSEQ*DDATA)     // 1800
#define CSIZE (NSAMP*NPD)   // 1030400
#define RSIZE (NSAMP*TD)    // 230400
#define DSIZE (TSEQ*NP)     // 5796

#define RT_N 11             // 176 padded rows / 16
#define KC_N 5              // k chunks of 32 (q=0..159); q=160 via rank-1
#define FRAG_CHUNK 512      // shorts per (rt,kc) fragment: 64 lanes * 8
#define YK 168              // padded k-dim of transposed Y

// dynamic LDS layout (bytes)
#define OFF_AF    0         // 55 chunks * (1024B H + 1024B L) = 112640
#define OFF_YH    112640    // 32*168*2 = 10752
#define OFF_YL    123392    // 10752
#define OFF_A160  134144    // 176*4 = 704
#define OFF_YREM  134848    // 32*4 = 128
#define OFF_CP    134976    // 4*2*16*4 = 512
#define OFF_SS    135488    // 32*4 = 128
#define LDS_BYTES 135616

typedef __attribute__((ext_vector_type(8))) short s8b;
typedef __attribute__((ext_vector_type(4))) float f4;

__device__ __forceinline__ unsigned short f2b(float f) {
    unsigned u = __float_as_uint(f);
    unsigned r = (u + 0x7FFFu + ((u >> 16) & 1u)) >> 16;   // RNE to bf16
    return (unsigned short)r;
}
__device__ __forceinline__ float b2f(unsigned short h) {
    return __uint_as_float(((unsigned)h) << 16);
}

// ---------------- D matrix (clamped poles) ----------------------------------
__global__ void k_build_D(const float* __restrict__ rho, const float* __restrict__ theta,
                          float* __restrict__ Dw, float* __restrict__ Dout) {
    int idx = blockIdx.x * 256 + threadIdx.x;
    if (idx >= DSIZE) return;
    int t = idx / NP, p = idx - (idx / NP) * NP;
    float v;
    if (p == 0) {
        v = 1.f;
    } else {
        int j = (p <= NPOLES) ? (p - 1) : (p - 1 - NPOLES);
        float r  = fminf(fmaxf(rho[j],   0.8f), 1.1f);
        float th = fminf(fmaxf(theta[j], 0.1f), 3.14159265358979323846f);
        double pw  = pow((double)r, (double)t);
        double ang = (double)t * (double)th;
        v = (float)(pw * ((p <= NPOLES) ? cos(ang) : sin(ang)));
    }
    Dw[idx] = v;
    Dout[idx] = v;
}

// ---------------- DDt = D @ D^T  [36x36] ------------------------------------
__global__ void k_ddt(const float* __restrict__ Dw, float* __restrict__ DDt) {
    int idx = blockIdx.x * 256 + threadIdx.x;
    if (idx >= TSEQ * TSEQ) return;
    int i = idx / TSEQ, j = idx - (idx / TSEQ) * TSEQ;
    float acc = 0.f;
    for (int p = 0; p < NP; ++p) acc = fmaf(Dw[i * NP + p], Dw[j * NP + p], acc);
    DDt[idx] = acc;
}

// ---------------- power iteration -> scal[0]=1/L ----------------------------
__global__ void k_power(const float* __restrict__ DDt, float* __restrict__ scal) {
    __shared__ float sM[TSEQ * TSEQ];
    __shared__ float sv[TSEQ];
    int tid = threadIdx.x;  // 64 threads = 1 wave
    for (int i = tid; i < TSEQ * TSEQ; i += 64) sM[i] = DDt[i];
    if (tid < TSEQ) sv[tid] = 1.f;
    __syncthreads();
    for (int it = 0; it < 150; ++it) {
        float u = 0.f;
        if (tid < TSEQ) {
            for (int q = 0; q < TSEQ; ++q) u = fmaf(sM[tid * TSEQ + q], sv[q], u);
        }
        float nn = u * u;
        for (int o = 32; o > 0; o >>= 1) nn += __shfl_down(nn, o);
        nn = __shfl(nn, 0);
        float inv = rsqrtf(nn);
        __syncthreads();
        if (tid < TSEQ) sv[tid] = u * inv;
        __syncthreads();
    }
    float rq = 0.f;
    if (tid < TSEQ) {
        float uu = 0.f;
        for (int q = 0; q < TSEQ; ++q) uu = fmaf(sM[tid * TSEQ + q], sv[q], uu);
        rq = uu * sv[tid];
    }
    for (int o = 32; o > 0; o >>= 1) rq += __shfl_down(rq, o);
    if (tid == 0) { scal[0] = 1.f / rq; scal[1] = rq; }
}

// ---------------- A = I - DtD/L, padded symmetric [q][p] --------------------
__global__ void k_A(const float* __restrict__ Dw, const float* __restrict__ scal,
                    float* __restrict__ Apad) {
    int idx = blockIdx.x * 256 + threadIdx.x;
    if (idx >= NP * NPAD) return;
    int q = idx / NPAD, p = idx - (idx / NPAD) * NPAD;
    float v = 0.f;
    if (p < NP) {
        float acc = 0.f;
        for (int t = 0; t < TSEQ; ++t) acc = fmaf(Dw[t * NP + q], Dw[t * NP + p], acc);
        v = ((p == q) ? 1.f : 0.f) - acc * scal[0];
    }
    Apad[idx] = v;
}

// ---------------- DtY[n,p,d] = sum_t D[t,p] * Y[n,t,d] ----------------------
__global__ void k_dty(const float* __restrict__ Dw, const float* __restrict__ Y,
                      float* __restrict__ dty) {
    int idx = blockIdx.x * 256 + threadIdx.x;
    if (idx >= CSIZE) return;
    int n = idx / NPD;
    int r = idx - n * NPD;
    int p = r / DDATA;
    int d = r - p * DDATA;
    const float* yp = Y + n * TD + d;
    float acc = 0.f;
    for (int t = 0; t < TSEQ; ++t) acc = fmaf(Dw[t * NP + p], yp[t * DDATA], acc);
    dty[idx] = acc;
}

// ---------------- pack A into MFMA fragment order, split bf16 hi/lo ---------
__global__ void k_Afrag(const float* __restrict__ Apad,
                        short* __restrict__ AfH, short* __restrict__ AfL) {
    int idx = blockIdx.x * 256 + threadIdx.x;
    if (idx >= RT_N * KC_N * 64) return;
    int lane = idx & 63;
    int chunk = idx >> 6;
    int kc = chunk % KC_N;
    int rt = chunk / KC_N;
    int p = rt * 16 + (lane & 15);
    int q0 = kc * 32 + (lane >> 4) * 8;
    int base = chunk * FRAG_CHUNK + lane * 8;
#pragma unroll
    for (int j = 0; j < 8; ++j) {
        int q = q0 + j;
        float v = (p < NP && q < NP) ? Apad[q * NPAD + p] : 0.f;  // A[p][q] (symmetric)
        unsigned short h = f2b(v);
        float rem = v - b2f(h);
        AfH[base + j] = (short)h;
        AfL[base + j] = (short)f2b(rem);
    }
}

// ---------------- persistent MFMA FISTA, A-fragments in LDS -----------------
// block=(n, d-half). 4 waves: wave w owns row-tiles rt0=w*3 (3,3,3,2),
// both col-tiles. A-fragments staged LDS-resident once.
__global__ __launch_bounds__(256, 1) void k_fista(
    const float* __restrict__ Apad,
    const uint4* __restrict__ AfH, const uint4* __restrict__ AfL,
    const float* __restrict__ dty_g, const float* __restrict__ scal,
    float* __restrict__ Cout)
{
    extern __shared__ char smem[];
    short* Af            = (short*)(smem + OFF_AF);     // [55][1024] shorts (H|L)
    unsigned short* Yhp  = (unsigned short*)(smem + OFF_YH);   // [32][YK]
    unsigned short* Ylp  = (unsigned short*)(smem + OFF_YL);
    float* A160          = (float*)(smem + OFF_A160);   // [176]
    float* yrem          = (float*)(smem + OFF_YREM);   // [32]
    float* colpart       = (float*)(smem + OFF_CP);     // [4][2][16]
    float* sS            = (float*)(smem + OFF_SS);     // [32]

    const int tid = threadIdx.x;
    const int n = blockIdx.x >> 1;
    const int dh = blockIdx.x & 1;
    const int w = tid >> 6;
    const int lane = tid & 63;
    const int c0 = lane & 15;
    const int g = lane >> 4;
    const int rt0 = w * 3;
    const int ntr = (w == 3) ? 2 : 3;
    const float Linv = scal[0];
    const float lamL = LAMF * Linv;

    // stage A fragments into LDS (one-time): chunk ck -> [H 64 uint4 | L 64 uint4]
    {
        uint4* dst = (uint4*)Af;
        for (int i = tid; i < RT_N * KC_N * 64; i += 256) {
            int ck = i >> 6, j = i & 63;
            dst[ck * 128 + j]      = AfH[i];
            dst[ck * 128 + 64 + j] = AfL[i];
        }
    }
    for (int i = tid; i < 176; i += 256)
        A160[i] = (i < NP) ? Apad[160 * NPAD + i] : 0.f;

    // per-thread tile geometry + dty*Linv (C/D layout: col=l&15, row=g*4+reg)
    float dtL[6][4];
    int rowb[6], colv[6];
#pragma unroll
    for (int i = 0; i < 6; ++i) {
        int rt = rt0 + (i >> 1);
        int ct = i & 1;
        rowb[i] = rt * 16 + g * 4;
        colv[i] = ct * 16 + c0;
#pragma unroll
        for (int r = 0; r < 4; ++r) {
            int row = rowb[i] + r;
            float v = 0.f;
            if (((i >> 1) < ntr) && row < NP && colv[i] < 25)
                v = dty_g[n * NPD + row * DDATA + dh * 25 + colv[i]];
            dtL[i][r] = v * Linv;
        }
    }

    float x_[6][4], wlam_[6][4];
#pragma unroll
    for (int i = 0; i < 6; ++i)
#pragma unroll
        for (int r = 0; r < 4; ++r) wlam_[i][r] = lamL;

#pragma unroll 1
    for (int round = 0; round < 2; ++round) {
#pragma unroll
        for (int i = 0; i < 6; ++i)
#pragma unroll
            for (int r = 0; r < 4; ++r) x_[i][r] = 0.f;
        {   // zero y state
            unsigned* ph = (unsigned*)Yhp;
            unsigned* pl = (unsigned*)Ylp;
            for (int i = tid; i < 32 * YK / 2; i += 256) { ph[i] = 0u; pl[i] = 0u; }
            if (tid < 32) yrem[tid] = 0.f;
        }
        float tmom = 1.f;
        __syncthreads();   // also covers one-time A staging before first use

#pragma unroll 1
        for (int it = 0; it < 100; ++it) {
            float tn = (1.f + sqrtf(fmaf(4.f * tmom, tmom, 1.f))) * 0.5f;
            float ttc = (tmom - 1.f) / tn;
            tmom = tn;

            f4 acc[6];
#pragma unroll
            for (int i = 0; i < 6; ++i) acc[i] = (f4){0.f, 0.f, 0.f, 0.f};

#pragma unroll
            for (int kc = 0; kc < KC_N; ++kc) {
                int yo = kc * 32 + g * 8;
                s8b bh0 = *(const s8b*)&Yhp[c0 * YK + yo];
                s8b bl0 = *(const s8b*)&Ylp[c0 * YK + yo];
                s8b bh1 = *(const s8b*)&Yhp[(16 + c0) * YK + yo];
                s8b bl1 = *(const s8b*)&Ylp[(16 + c0) * YK + yo];
#pragma unroll
                for (int rr = 0; rr < 3; ++rr) {
                    if (rr < ntr) {
                        int rt = rt0 + rr;
                        const s8b* Ab = (const s8b*)(Af + (rt * KC_N + kc) * 1024);
                        s8b ah = Ab[lane];
                        s8b al = Ab[64 + lane];
                        acc[2*rr]   = __builtin_amdgcn_mfma_f32_16x16x32_bf16(ah, bh0, acc[2*rr],   0, 0, 0);
                        acc[2*rr]   = __builtin_amdgcn_mfma_f32_16x16x32_bf16(ah, bl0, acc[2*rr],   0, 0, 0);
                        acc[2*rr]   = __builtin_amdgcn_mfma_f32_16x16x32_bf16(al, bh0, acc[2*rr],   0, 0, 0);
                        acc[2*rr+1] = __builtin_amdgcn_mfma_f32_16x16x32_bf16(ah, bh1, acc[2*rr+1], 0, 0, 0);
                        acc[2*rr+1] = __builtin_amdgcn_mfma_f32_16x16x32_bf16(ah, bl1, acc[2*rr+1], 0, 0, 0);
                        acc[2*rr+1] = __builtin_amdgcn_mfma_f32_16x16x32_bf16(al, bh1, acc[2*rr+1], 0, 0, 0);
                    }
                }
            }
            {   // q=160 rank-1 term in f32
                float y0 = yrem[c0];
                float y1 = yrem[16 + c0];
#pragma unroll
                for (int i = 0; i < 6; ++i) {
                    if ((i >> 1) < ntr) {
                        const f4 a4 = *(const f4*)&A160[rowb[i]];
                        float yv = (i & 1) ? y1 : y0;
                        acc[i] += a4 * yv;
                    }
                }
            }
            __syncthreads();   // all reads of y-state done

            // epilogue: soft-threshold + momentum + write y (bf16 split, transposed)
#pragma unroll
            for (int i = 0; i < 6; ++i) {
                if ((i >> 1) < ntr) {
                    unsigned short hh[4], ll[4];
                    float yn0 = 0.f;
#pragma unroll
                    for (int r = 0; r < 4; ++r) {
                        float bb = dtL[i][r] + acc[i][r];
                        float wl = wlam_[i][r];
                        float xn = fmaxf(bb - wl, 0.f) + fminf(bb + wl, 0.f);
                        float yn = fmaf(ttc, xn - x_[i][r], xn);
                        x_[i][r] = xn;
                        if (r == 0) yn0 = yn;
                        unsigned short h = f2b(yn);
                        hh[r] = h;
                        ll[r] = f2b(yn - b2f(h));
                    }
                    int rt = rt0 + (i >> 1);
                    if (rt < 10) {
                        uint2 hp, lp;
                        hp.x = (unsigned)hh[0] | ((unsigned)hh[1] << 16);
                        hp.y = (unsigned)hh[2] | ((unsigned)hh[3] << 16);
                        lp.x = (unsigned)ll[0] | ((unsigned)ll[1] << 16);
                        lp.y = (unsigned)ll[2] | ((unsigned)ll[3] << 16);
                        *(uint2*)&Yhp[colv[i] * YK + rowb[i]] = hp;
                        *(uint2*)&Ylp[colv[i] * YK + rowb[i]] = lp;
                    } else if (g == 0) {
                        yrem[colv[i]] = yn0;   // row 160 (rows >160 are pad, y=0)
                    }
                }
            }
            __syncthreads();   // y-state ready for next iter
        }

        if (round == 0) {
            // reweight: wlam = (1/(|x|+.01)) / colsum(1/(|x|+.01)) * NP * lamL
            float ps0 = 0.f, ps1 = 0.f;
#pragma unroll
            for (int i = 0; i < 6; ++i) {
                if ((i >> 1) < ntr) {
#pragma unroll
                    for (int r = 0; r < 4; ++r) {
                        if (rowb[i] + r < NP) {
                            float wi = 1.f / (fabsf(x_[i][r]) + 0.01f);
                            if (i & 1) ps1 += wi; else ps0 += wi;
                        }
                    }
                }
            }
            ps0 += __shfl_xor(ps0, 16); ps0 += __shfl_xor(ps0, 32);
            ps1 += __shfl_xor(ps1, 16); ps1 += __shfl_xor(ps1, 32);
            if (lane < 16) { colpart[(w * 2 + 0) * 16 + lane] = ps0;
                             colpart[(w * 2 + 1) * 16 + lane] = ps1; }
            __syncthreads();
            if (tid < 32) {
                int ct = tid >> 4, cc = tid & 15;
                float s = colpart[(0 + ct) * 16 + cc] + colpart[(2 + ct) * 16 + cc]
                        + colpart[(4 + ct) * 16 + cc] + colpart[(6 + ct) * 16 + cc];
                sS[tid] = (float)NP / s;
            }
            __syncthreads();
#pragma unroll
            for (int i = 0; i < 6; ++i) {
                float sc = sS[colv[i]] * lamL;
#pragma unroll
                for (int r = 0; r < 4; ++r)
                    wlam_[i][r] = (1.f / (fabsf(x_[i][r]) + 0.01f)) * sc;
            }
            __syncthreads();
        }
    }

    // store C (f32)
#pragma unroll
    for (int i = 0; i < 6; ++i) {
        if (((i >> 1) < ntr) && colv[i] < 25) {
#pragma unroll
            for (int r = 0; r < 4; ++r) {
                int row = rowb[i] + r;
                if (row < NP)
                    Cout[n * NPD + row * DDATA + dh * 25 + colv[i]] = x_[i][r];
            }
        }
    }
}

// ---------------- R = D @ C ------------------------------------------------
__global__ void k_R(const float* __restrict__ Dw, const float* __restrict__ Cf,
                    float* __restrict__ Rout) {
    int idx = blockIdx.x * 256 + threadIdx.x;
    if (idx >= RSIZE) return;
    int n = idx / TD;
    int r = idx - n * TD;
    int t = r / DDATA;
    int d = r - t * DDATA;
    const float* xp = Cf + n * NPD + d;
    float acc = 0.f;
    for (int p = 0; p < NP; ++p) acc = fmaf(Dw[t * NP + p], xp[p * DDATA], acc);
    Rout[idx] = acc;
}

extern "C" void kernel_launch(void* const* d_in, const int* in_sizes, int n_in,
                              void* d_out, int out_size, void* d_ws, size_t ws_size,
                              hipStream_t stream) {
    const float* Y     = (const float*)d_in[0];
    const float* rho   = (const float*)d_in[1];
    const float* theta = (const float*)d_in[2];
    float* Cout = (float*)d_out;
    float* Dout = Cout + CSIZE;
    float* Rout = Dout + DSIZE;

    float* ws    = (float*)d_ws;
    float* Dw    = ws;                 // 5824
    float* Apad  = Dw + 5824;          // 26416
    float* DDt   = Apad + 26416;       // 1312
    float* scal  = DDt + 1312;         // 16
    float* dty   = scal + 16;          // CSIZE
    float* AfH_f = dty + CSIZE;        // 14080 floats (= 28160 shorts)
    float* AfL_f = AfH_f + 14080;      // 14080 floats

    k_build_D<<<(DSIZE + 255) / 256, 256, 0, stream>>>(rho, theta, Dw, Dout);
    k_ddt<<<(TSEQ * TSEQ + 255) / 256, 256, 0, stream>>>(Dw, DDt);
    k_power<<<1, 64, 0, stream>>>(DDt, scal);
    k_A<<<(NP * NPAD + 255) / 256, 256, 0, stream>>>(Dw, scal, Apad);
    k_dty<<<(CSIZE + 255) / 256, 256, 0, stream>>>(Dw, Y, dty);
    k_Afrag<<<(RT_N * KC_N * 64 + 255) / 256, 256, 0, stream>>>(Apad, (short*)AfH_f, (short*)AfL_f);

    hipFuncSetAttribute((const void*)k_fista,
                        hipFuncAttributeMaxDynamicSharedMemorySize, LDS_BYTES);
    k_fista<<<NSAMP * 2, 256, LDS_BYTES, stream>>>(Apad, (const uint4*)AfH_f, (const uint4*)AfL_f,
                                                   dty, scal, Cout);

    k_R<<<(RSIZE + 255) / 256, 256, 0, stream>>>(Dw, Cout, Rout);
}

// Round 6
// 430.373 us; speedup vs baseline: 15.8660x; 1.4689x over previous
//
#include <hip/hip_runtime.h>
#include <math.h>

#define NPOLES 80
#define NP 161          // 2*NPOLES+1
#define NPAD 164
#define TSEQ 36
#define NSAMP 128
#define DDATA 50
#define LAMF 0.1f
#define NPD (NP*DDATA)      // 8050
#define TD (TSEQ*DDATA)     // 1800
#define CSIZE (NSAMP*NPD)   // 1030400
#define RSIZE (NSAMP*TD)    // 230400
#define DSIZE (TSEQ*NP)     // 5796

#define RT_N 11             // 176 padded rows / 16
#define KC_N 5              // k chunks of 32 (q=0..159); q=160 via rank-1
#define FRAG_CHUNK 512      // shorts per (rt,kc) fragment: 64 lanes * 8
#define YK 168              // padded k-dim of transposed Y (336B rows, 16B-aligned)

typedef __attribute__((ext_vector_type(8))) short s8b;
typedef __attribute__((ext_vector_type(4))) float f4;

__device__ __forceinline__ unsigned short f2b(float f) {
    unsigned u = __float_as_uint(f);
    unsigned r = (u + 0x7FFFu + ((u >> 16) & 1u)) >> 16;   // RNE to bf16
    return (unsigned short)r;
}
__device__ __forceinline__ float b2f(unsigned short h) {
    return __uint_as_float(((unsigned)h) << 16);
}

// ---------------- D matrix (clamped poles) ----------------------------------
__global__ void k_build_D(const float* __restrict__ rho, const float* __restrict__ theta,
                          float* __restrict__ Dw, float* __restrict__ Dout) {
    int idx = blockIdx.x * 256 + threadIdx.x;
    if (idx >= DSIZE) return;
    int t = idx / NP, p = idx - (idx / NP) * NP;
    float v;
    if (p == 0) {
        v = 1.f;
    } else {
        int j = (p <= NPOLES) ? (p - 1) : (p - 1 - NPOLES);
        float r  = fminf(fmaxf(rho[j],   0.8f), 1.1f);
        float th = fminf(fmaxf(theta[j], 0.1f), 3.14159265358979323846f);
        double pw  = pow((double)r, (double)t);
        double ang = (double)t * (double)th;
        v = (float)(pw * ((p <= NPOLES) ? cos(ang) : sin(ang)));
    }
    Dw[idx] = v;
    Dout[idx] = v;
}

// ---------------- DDt = D @ D^T  [36x36] ------------------------------------
__global__ void k_ddt(const float* __restrict__ Dw, float* __restrict__ DDt) {
    int idx = blockIdx.x * 256 + threadIdx.x;
    if (idx >= TSEQ * TSEQ) return;
    int i = idx / TSEQ, j = idx - (idx / TSEQ) * TSEQ;
    float acc = 0.f;
    for (int p = 0; p < NP; ++p) acc = fmaf(Dw[i * NP + p], Dw[j * NP + p], acc);
    DDt[idx] = acc;
}

// ---------------- power iteration -> scal[0]=1/L ----------------------------
__global__ void k_power(const float* __restrict__ DDt, float* __restrict__ scal) {
    __shared__ float sM[TSEQ * TSEQ];
    __shared__ float sv[TSEQ];
    int tid = threadIdx.x;  // 64 threads = 1 wave
    for (int i = tid; i < TSEQ * TSEQ; i += 64) sM[i] = DDt[i];
    if (tid < TSEQ) sv[tid] = 1.f;
    __syncthreads();
    for (int it = 0; it < 150; ++it) {
        float u = 0.f;
        if (tid < TSEQ) {
            for (int q = 0; q < TSEQ; ++q) u = fmaf(sM[tid * TSEQ + q], sv[q], u);
        }
        float nn = u * u;
        for (int o = 32; o > 0; o >>= 1) nn += __shfl_down(nn, o);
        nn = __shfl(nn, 0);
        float inv = rsqrtf(nn);
        __syncthreads();
        if (tid < TSEQ) sv[tid] = u * inv;
        __syncthreads();
    }
    float rq = 0.f;
    if (tid < TSEQ) {
        float uu = 0.f;
        for (int q = 0; q < TSEQ; ++q) uu = fmaf(sM[tid * TSEQ + q], sv[q], uu);
        rq = uu * sv[tid];
    }
    for (int o = 32; o > 0; o >>= 1) rq += __shfl_down(rq, o);
    if (tid == 0) { scal[0] = 1.f / rq; scal[1] = rq; }
}

// ---------------- A = I - DtD/L, padded symmetric [q][p] --------------------
__global__ void k_A(const float* __restrict__ Dw, const float* __restrict__ scal,
                    float* __restrict__ Apad) {
    int idx = blockIdx.x * 256 + threadIdx.x;
    if (idx >= NP * NPAD) return;
    int q = idx / NPAD, p = idx - (idx / NPAD) * NPAD;
    float v = 0.f;
    if (p < NP) {
        float acc = 0.f;
        for (int t = 0; t < TSEQ; ++t) acc = fmaf(Dw[t * NP + q], Dw[t * NP + p], acc);
        v = ((p == q) ? 1.f : 0.f) - acc * scal[0];
    }
    Apad[idx] = v;
}

// ---------------- DtY[n,p,d] = sum_t D[t,p] * Y[n,t,d] ----------------------
__global__ void k_dty(const float* __restrict__ Dw, const float* __restrict__ Y,
                      float* __restrict__ dty) {
    int idx = blockIdx.x * 256 + threadIdx.x;
    if (idx >= CSIZE) return;
    int n = idx / NPD;
    int r = idx - n * NPD;
    int p = r / DDATA;
    int d = r - p * DDATA;
    const float* yp = Y + n * TD + d;
    float acc = 0.f;
    for (int t = 0; t < TSEQ; ++t) acc = fmaf(Dw[t * NP + p], yp[t * DDATA], acc);
    dty[idx] = acc;
}

// ---------------- pack A into MFMA fragment order, split bf16 hi/lo ---------
__global__ void k_Afrag(const float* __restrict__ Apad,
                        short* __restrict__ AfH, short* __restrict__ AfL) {
    int idx = blockIdx.x * 256 + threadIdx.x;
    if (idx >= RT_N * KC_N * 64) return;
    int lane = idx & 63;
    int chunk = idx >> 6;
    int kc = chunk % KC_N;
    int rt = chunk / KC_N;
    int p = rt * 16 + (lane & 15);
    int q0 = kc * 32 + (lane >> 4) * 8;
    int base = chunk * FRAG_CHUNK + lane * 8;
#pragma unroll
    for (int j = 0; j < 8; ++j) {
        int q = q0 + j;
        float v = (p < NP && q < NP) ? Apad[q * NPAD + p] : 0.f;  // A[p][q] (symmetric)
        unsigned short h = f2b(v);
        float rem = v - b2f(h);
        AfH[base + j] = (short)h;
        AfL[base + j] = (short)f2b(rem);
    }
}

// ---------------- persistent MFMA FISTA, A-fragments in REGISTERS -----------
// block=(n, col-quarter dq: 13,13,13,11 cols). grid 512 -> 2 blocks/CU.
// 4 waves: wave w owns row-tiles rt0=w*3 (3,3,3,2), one 16-col tile.
__global__ __launch_bounds__(256, 2) void k_fista(
    const float* __restrict__ Apad,
    const s8b* __restrict__ AfH, const s8b* __restrict__ AfL,
    const float* __restrict__ dty_g, const float* __restrict__ scal,
    float* __restrict__ Cout)
{
    __shared__ unsigned short Yh[16][YK];   // y transposed [col][k], bf16 hi
    __shared__ unsigned short Yl[16][YK];   // bf16 lo
    __shared__ float yrem[16];              // y[row 160][col] f32
    __shared__ float colpart[4][16];
    __shared__ float sS[16];

    const int tid = threadIdx.x;
    const int n  = blockIdx.x >> 2;
    const int dq = blockIdx.x & 3;
    const int w = tid >> 6;
    const int lane = tid & 63;
    const int c0 = lane & 15;
    const int g = lane >> 4;
    const int rt0 = w * 3;
    const int ntr = (w == 3) ? 2 : 3;
    const int ncol = (dq == 3) ? 11 : 13;
    const int colv = dq * 13 + c0;
    const bool cvalid = c0 < ncol;
    const float Linv = scal[0];
    const float lamL = LAMF * Linv;

    // ---- persistent A fragments in registers (one-time coalesced load) ----
    s8b ahr[3][KC_N], alr[3][KC_N];
    const s8b zer = {0, 0, 0, 0, 0, 0, 0, 0};
#pragma unroll
    for (int rr = 0; rr < 3; ++rr) {
#pragma unroll
        for (int kc = 0; kc < KC_N; ++kc) {
            if (rr < ntr) {
                int ck = (rt0 + rr) * KC_N + kc;
                ahr[rr][kc] = AfH[ck * 64 + lane];
                alr[rr][kc] = AfL[ck * 64 + lane];
            } else {
                ahr[rr][kc] = zer;
                alr[rr][kc] = zer;
            }
        }
    }

    // tile geometry + dty*Linv + A[:,160] rows (C/D layout: col=l&15, row=g*4+reg)
    int rowb[3];
    float dtL[3][4];
    f4 a160r[3];
#pragma unroll
    for (int rr = 0; rr < 3; ++rr) {
        rowb[rr] = (rt0 + rr) * 16 + g * 4;
#pragma unroll
        for (int r = 0; r < 4; ++r) {
            int row = rowb[rr] + r;
            float v = 0.f;
            if ((rr < ntr) && row < NP && cvalid)
                v = dty_g[n * NPD + row * DDATA + colv];
            dtL[rr][r] = v * Linv;
            a160r[rr][r] = ((rr < ntr) && row < NP) ? Apad[160 * NPAD + row] : 0.f;
        }
    }

    float x_[3][4], wlam_[3][4];
#pragma unroll
    for (int rr = 0; rr < 3; ++rr)
#pragma unroll
        for (int r = 0; r < 4; ++r) wlam_[rr][r] = lamL;

#pragma unroll 1
    for (int round = 0; round < 2; ++round) {
#pragma unroll
        for (int rr = 0; rr < 3; ++rr)
#pragma unroll
            for (int r = 0; r < 4; ++r) x_[rr][r] = 0.f;
        {   // zero y state
            unsigned* ph = (unsigned*)&Yh[0][0];
            unsigned* pl = (unsigned*)&Yl[0][0];
            for (int i = tid; i < 16 * YK / 2; i += 256) { ph[i] = 0u; pl[i] = 0u; }
            if (tid < 16) yrem[tid] = 0.f;
        }
        float tmom = 1.f;
        __syncthreads();

#pragma unroll 1
        for (int it = 0; it < 100; ++it) {
            float tn = (1.f + sqrtf(fmaf(4.f * tmom, tmom, 1.f))) * 0.5f;
            float ttc = (tmom - 1.f) / tn;
            tmom = tn;

            f4 acc[3];
#pragma unroll
            for (int rr = 0; rr < 3; ++rr) acc[rr] = (f4){0.f, 0.f, 0.f, 0.f};

#pragma unroll
            for (int kc = 0; kc < KC_N; ++kc) {
                int yo = kc * 32 + g * 8;
                s8b bh = *(const s8b*)&Yh[c0][yo];
                s8b bl = *(const s8b*)&Yl[c0][yo];
#pragma unroll
                for (int rr = 0; rr < 3; ++rr) {
                    if (rr < ntr) {
                        acc[rr] = __builtin_amdgcn_mfma_f32_16x16x32_bf16(ahr[rr][kc], bh, acc[rr], 0, 0, 0);
                        acc[rr] = __builtin_amdgcn_mfma_f32_16x16x32_bf16(ahr[rr][kc], bl, acc[rr], 0, 0, 0);
                        acc[rr] = __builtin_amdgcn_mfma_f32_16x16x32_bf16(alr[rr][kc], bh, acc[rr], 0, 0, 0);
                    }
                }
            }
            {   // q=160 rank-1 term in f32
                float yv = yrem[c0];
#pragma unroll
                for (int rr = 0; rr < 3; ++rr)
                    if (rr < ntr) acc[rr] += a160r[rr] * yv;
            }
            __syncthreads();   // all reads of y-state done

            // epilogue: soft-threshold + momentum + write y (bf16 split, transposed)
#pragma unroll
            for (int rr = 0; rr < 3; ++rr) {
                if (rr < ntr) {
                    unsigned short hh[4], ll[4];
                    float yn0 = 0.f;
#pragma unroll
                    for (int r = 0; r < 4; ++r) {
                        float bb = dtL[rr][r] + acc[rr][r];
                        float wl = wlam_[rr][r];
                        float xn = fmaxf(bb - wl, 0.f) + fminf(bb + wl, 0.f);
                        float yn = fmaf(ttc, xn - x_[rr][r], xn);
                        x_[rr][r] = xn;
                        if (r == 0) yn0 = yn;
                        unsigned short h = f2b(yn);
                        hh[r] = h;
                        ll[r] = f2b(yn - b2f(h));
                    }
                    int rt = rt0 + rr;
                    if (rt < 10) {
                        uint2 hp, lp;
                        hp.x = (unsigned)hh[0] | ((unsigned)hh[1] << 16);
                        hp.y = (unsigned)hh[2] | ((unsigned)hh[3] << 16);
                        lp.x = (unsigned)ll[0] | ((unsigned)ll[1] << 16);
                        lp.y = (unsigned)ll[2] | ((unsigned)ll[3] << 16);
                        *(uint2*)&Yh[c0][rowb[rr]] = hp;
                        *(uint2*)&Yl[c0][rowb[rr]] = lp;
                    } else if (g == 0) {
                        yrem[c0] = yn0;   // row 160 (rows >160 are pad, y=0)
                    }
                }
            }
            __syncthreads();   // y-state ready for next iter
        }

        if (round == 0) {
            // reweight: wlam = (1/(|x|+.01)) / colsum(1/(|x|+.01)) * NP * lamL
            float ps = 0.f;
#pragma unroll
            for (int rr = 0; rr < 3; ++rr) {
                if (rr < ntr) {
#pragma unroll
                    for (int r = 0; r < 4; ++r) {
                        if (rowb[rr] + r < NP)
                            ps += 1.f / (fabsf(x_[rr][r]) + 0.01f);
                    }
                }
            }
            ps += __shfl_xor(ps, 16);
            ps += __shfl_xor(ps, 32);
            if (lane < 16) colpart[w][lane] = ps;
            __syncthreads();
            if (tid < 16) {
                float s = colpart[0][tid] + colpart[1][tid] + colpart[2][tid] + colpart[3][tid];
                sS[tid] = (float)NP / s;
            }
            __syncthreads();
            float sc = sS[c0] * lamL;
#pragma unroll
            for (int rr = 0; rr < 3; ++rr)
#pragma unroll
                for (int r = 0; r < 4; ++r)
                    wlam_[rr][r] = (1.f / (fabsf(x_[rr][r]) + 0.01f)) * sc;
            __syncthreads();
        }
    }

    // store C (f32)
#pragma unroll
    for (int rr = 0; rr < 3; ++rr) {
        if ((rr < ntr) && cvalid) {
#pragma unroll
            for (int r = 0; r < 4; ++r) {
                int row = rowb[rr] + r;
                if (row < NP)
                    Cout[n * NPD + row * DDATA + colv] = x_[rr][r];
            }
        }
    }
}

// ---------------- R = D @ C ------------------------------------------------
__global__ void k_R(const float* __restrict__ Dw, const float* __restrict__ Cf,
                    float* __restrict__ Rout) {
    int idx = blockIdx.x * 256 + threadIdx.x;
    if (idx >= RSIZE) return;
    int n = idx / TD;
    int r = idx - n * TD;
    int t = r / DDATA;
    int d = r - t * DDATA;
    const float* xp = Cf + n * NPD + d;
    float acc = 0.f;
    for (int p = 0; p < NP; ++p) acc = fmaf(Dw[t * NP + p], xp[p * DDATA], acc);
    Rout[idx] = acc;
}

extern "C" void kernel_launch(void* const* d_in, const int* in_sizes, int n_in,
                              void* d_out, int out_size, void* d_ws, size_t ws_size,
                              hipStream_t stream) {
    const float* Y     = (const float*)d_in[0];
    const float* rho   = (const float*)d_in[1];
    const float* theta = (const float*)d_in[2];
    float* Cout = (float*)d_out;
    float* Dout = Cout + CSIZE;
    float* Rout = Dout + DSIZE;

    float* ws    = (float*)d_ws;
    float* Dw    = ws;                 // 5824
    float* Apad  = Dw + 5824;          // 26416
    float* DDt   = Apad + 26416;       // 1312
    float* scal  = DDt + 1312;         // 16
    float* dty   = scal + 16;          // CSIZE
    float* AfH_f = dty + CSIZE;        // 14080 floats (= 28160 shorts)
    float* AfL_f = AfH_f + 14080;      // 14080 floats

    k_build_D<<<(DSIZE + 255) / 256, 256, 0, stream>>>(rho, theta, Dw, Dout);
    k_ddt<<<(TSEQ * TSEQ + 255) / 256, 256, 0, stream>>>(Dw, DDt);
    k_power<<<1, 64, 0, stream>>>(DDt, scal);
    k_A<<<(NP * NPAD + 255) / 256, 256, 0, stream>>>(Dw, scal, Apad);
    k_dty<<<(CSIZE + 255) / 256, 256, 0, stream>>>(Dw, Y, dty);
    k_Afrag<<<(RT_N * KC_N * 64 + 255) / 256, 256, 0, stream>>>(Apad, (short*)AfH_f, (short*)AfL_f);

    k_fista<<<NSAMP * 4, 256, 0, stream>>>(Apad, (const s8b*)AfH_f, (const s8b*)AfL_f,
                                           dty, scal, Cout);

    k_R<<<(RSIZE + 255) / 256, 256, 0, stream>>>(Dw, Cout, Rout);
}

// Round 7
// 394.800 us; speedup vs baseline: 17.2956x; 1.0901x over previous
//
#include <hip/hip_runtime.h>
#include <math.h>

#define NPOLES 80
#define NP 161          // 2*NPOLES+1
#define NPAD 164
#define TSEQ 36
#define NSAMP 128
#define DDATA 50
#define LAMF 0.1f
#define NPD (NP*DDATA)      // 8050
#define TD (TSEQ*DDATA)     // 1800
#define CSIZE (NSAMP*NPD)   // 1030400
#define RSIZE (NSAMP*TD)    // 230400
#define DSIZE (TSEQ*NP)     // 5796

#define RT_N 11             // 176 padded rows / 16
#define KC_N 5              // k chunks of 32 (q=0..159); q=160 via rank-1
#define FRAG_CHUNK 512      // shorts per (rt,kc) fragment: 64 lanes * 8
#define YK 168              // padded k-dim of transposed Y (336B rows, 16B-aligned)

typedef __attribute__((ext_vector_type(8))) short s8b;
typedef __attribute__((ext_vector_type(4))) float f4;

__device__ __forceinline__ unsigned short f2b(float f) {
    unsigned u = __float_as_uint(f);
    unsigned r = (u + 0x7FFFu + ((u >> 16) & 1u)) >> 16;   // RNE to bf16
    return (unsigned short)r;
}
__device__ __forceinline__ float b2f(unsigned short h) {
    return __uint_as_float(((unsigned)h) << 16);
}

// ---------------- D matrix (clamped poles) ----------------------------------
__global__ void k_build_D(const float* __restrict__ rho, const float* __restrict__ theta,
                          float* __restrict__ Dw, float* __restrict__ Dout) {
    int idx = blockIdx.x * 256 + threadIdx.x;
    if (idx >= DSIZE) return;
    int t = idx / NP, p = idx - (idx / NP) * NP;
    float v;
    if (p == 0) {
        v = 1.f;
    } else {
        int j = (p <= NPOLES) ? (p - 1) : (p - 1 - NPOLES);
        float r  = fminf(fmaxf(rho[j],   0.8f), 1.1f);
        float th = fminf(fmaxf(theta[j], 0.1f), 3.14159265358979323846f);
        double pw  = pow((double)r, (double)t);
        double ang = (double)t * (double)th;
        v = (float)(pw * ((p <= NPOLES) ? cos(ang) : sin(ang)));
    }
    Dw[idx] = v;
    Dout[idx] = v;
}

// ---------------- DDt = D @ D^T  [36x36] ------------------------------------
__global__ void k_ddt(const float* __restrict__ Dw, float* __restrict__ DDt) {
    int idx = blockIdx.x * 256 + threadIdx.x;
    if (idx >= TSEQ * TSEQ) return;
    int i = idx / TSEQ, j = idx - (idx / TSEQ) * TSEQ;
    float acc = 0.f;
    for (int p = 0; p < NP; ++p) acc = fmaf(Dw[i * NP + p], Dw[j * NP + p], acc);
    DDt[idx] = acc;
}

// ---------------- power iteration -> scal[0]=1/L ----------------------------
__global__ void k_power(const float* __restrict__ DDt, float* __restrict__ scal) {
    __shared__ float sM[TSEQ * TSEQ];
    __shared__ float sv[TSEQ];
    int tid = threadIdx.x;  // 64 threads = 1 wave
    for (int i = tid; i < TSEQ * TSEQ; i += 64) sM[i] = DDt[i];
    if (tid < TSEQ) sv[tid] = 1.f;
    __syncthreads();
    for (int it = 0; it < 150; ++it) {
        float u = 0.f;
        if (tid < TSEQ) {
            for (int q = 0; q < TSEQ; ++q) u = fmaf(sM[tid * TSEQ + q], sv[q], u);
        }
        float nn = u * u;
        for (int o = 32; o > 0; o >>= 1) nn += __shfl_down(nn, o);
        nn = __shfl(nn, 0);
        float inv = rsqrtf(nn);
        __syncthreads();
        if (tid < TSEQ) sv[tid] = u * inv;
        __syncthreads();
    }
    float rq = 0.f;
    if (tid < TSEQ) {
        float uu = 0.f;
        for (int q = 0; q < TSEQ; ++q) uu = fmaf(sM[tid * TSEQ + q], sv[q], uu);
        rq = uu * sv[tid];
    }
    for (int o = 32; o > 0; o >>= 1) rq += __shfl_down(rq, o);
    if (tid == 0) { scal[0] = 1.f / rq; scal[1] = rq; }
}

// ---------------- A = I - DtD/L, padded symmetric [q][p] --------------------
__global__ void k_A(const float* __restrict__ Dw, const float* __restrict__ scal,
                    float* __restrict__ Apad) {
    int idx = blockIdx.x * 256 + threadIdx.x;
    if (idx >= NP * NPAD) return;
    int q = idx / NPAD, p = idx - (idx / NPAD) * NPAD;
    float v = 0.f;
    if (p < NP) {
        float acc = 0.f;
        for (int t = 0; t < TSEQ; ++t) acc = fmaf(Dw[t * NP + q], Dw[t * NP + p], acc);
        v = ((p == q) ? 1.f : 0.f) - acc * scal[0];
    }
    Apad[idx] = v;
}

// ---------------- DtY[n,p,d] = sum_t D[t,p] * Y[n,t,d] ----------------------
__global__ void k_dty(const float* __restrict__ Dw, const float* __restrict__ Y,
                      float* __restrict__ dty) {
    int idx = blockIdx.x * 256 + threadIdx.x;
    if (idx >= CSIZE) return;
    int n = idx / NPD;
    int r = idx - n * NPD;
    int p = r / DDATA;
    int d = r - p * DDATA;
    const float* yp = Y + n * TD + d;
    float acc = 0.f;
    for (int t = 0; t < TSEQ; ++t) acc = fmaf(Dw[t * NP + p], yp[t * DDATA], acc);
    dty[idx] = acc;
}

// ---------------- pack A into MFMA fragment order, split bf16 hi/lo ---------
__global__ void k_Afrag(const float* __restrict__ Apad,
                        short* __restrict__ AfH, short* __restrict__ AfL) {
    int idx = blockIdx.x * 256 + threadIdx.x;
    if (idx >= RT_N * KC_N * 64) return;
    int lane = idx & 63;
    int chunk = idx >> 6;
    int kc = chunk % KC_N;
    int rt = chunk / KC_N;
    int p = rt * 16 + (lane & 15);
    int q0 = kc * 32 + (lane >> 4) * 8;
    int base = chunk * FRAG_CHUNK + lane * 8;
#pragma unroll
    for (int j = 0; j < 8; ++j) {
        int q = q0 + j;
        float v = (p < NP && q < NP) ? Apad[q * NPAD + p] : 0.f;  // A[p][q] (symmetric)
        unsigned short h = f2b(v);
        float rem = v - b2f(h);
        AfH[base + j] = (short)h;
        AfL[base + j] = (short)f2b(rem);
    }
}

// ---------------- persistent MFMA FISTA, A in regs, dbuf y, 1 barrier/iter --
// block=(n, col-quarter dq: 13,13,13,11 cols). grid 512 -> 2 blocks/CU.
// 4 waves: wave w owns row-tiles rt0=w*3 (3,3,3,2), one 16-col tile.
__global__ __launch_bounds__(256, 2) void k_fista(
    const float* __restrict__ Apad,
    const s8b* __restrict__ AfH, const s8b* __restrict__ AfL,
    const float* __restrict__ dty_g, const float* __restrict__ scal,
    float* __restrict__ Cout)
{
    __shared__ unsigned short Yh[2][16][YK];   // y transposed [col][k], bf16 hi
    __shared__ unsigned short Yl[2][16][YK];   // bf16 lo
    __shared__ float yrem[2][16];              // y[row 160][col] f32
    __shared__ float colpart[4][16];
    __shared__ float sS[16];

    const int tid = threadIdx.x;
    const int n  = blockIdx.x >> 2;
    const int dq = blockIdx.x & 3;
    const int w = tid >> 6;
    const int lane = tid & 63;
    const int c0 = lane & 15;
    const int g = lane >> 4;
    const int rt0 = w * 3;
    const int ntr = (w == 3) ? 2 : 3;
    const int ncol = (dq == 3) ? 11 : 13;
    const int colv = dq * 13 + c0;
    const bool cvalid = c0 < ncol;
    const float Linv = scal[0];
    const float lamL = LAMF * Linv;

    // ---- persistent A fragments in registers (one-time coalesced load) ----
    s8b ahr[3][KC_N], alr[3][KC_N];
    const s8b zer = {0, 0, 0, 0, 0, 0, 0, 0};
#pragma unroll
    for (int rr = 0; rr < 3; ++rr) {
#pragma unroll
        for (int kc = 0; kc < KC_N; ++kc) {
            if (rr < ntr) {
                int ck = (rt0 + rr) * KC_N + kc;
                ahr[rr][kc] = AfH[ck * 64 + lane];
                alr[rr][kc] = AfL[ck * 64 + lane];
            } else {
                ahr[rr][kc] = zer;
                alr[rr][kc] = zer;
            }
        }
    }

    // tile geometry + dty*Linv + A[:,160] rows (C/D layout: col=l&15, row=g*4+reg)
    int rowb[3];
    float dtL[3][4];
    f4 a160r[3];
#pragma unroll
    for (int rr = 0; rr < 3; ++rr) {
        rowb[rr] = (rt0 + rr) * 16 + g * 4;
#pragma unroll
        for (int r = 0; r < 4; ++r) {
            int row = rowb[rr] + r;
            float v = 0.f;
            if ((rr < ntr) && row < NP && cvalid)
                v = dty_g[n * NPD + row * DDATA + colv];
            dtL[rr][r] = v * Linv;
            a160r[rr][r] = ((rr < ntr) && row < NP) ? Apad[160 * NPAD + row] : 0.f;
        }
    }

    float x_[3][4], wlam_[3][4];
#pragma unroll
    for (int rr = 0; rr < 3; ++rr)
#pragma unroll
        for (int r = 0; r < 4; ++r) wlam_[rr][r] = lamL;

#pragma unroll 1
    for (int round = 0; round < 2; ++round) {
#pragma unroll
        for (int rr = 0; rr < 3; ++rr)
#pragma unroll
            for (int r = 0; r < 4; ++r) x_[rr][r] = 0.f;
        {   // zero read-buffer (index 0); write-buffer fully overwritten at it 0
            unsigned* ph = (unsigned*)&Yh[0][0][0];
            unsigned* pl = (unsigned*)&Yl[0][0][0];
            for (int i = tid; i < 16 * YK / 2; i += 256) { ph[i] = 0u; pl[i] = 0u; }
            if (tid < 16) yrem[0][tid] = 0.f;
        }
        float tmom = 1.f;
        int cur = 0;
        __syncthreads();

#pragma unroll 1
        for (int it = 0; it < 100; ++it) {
            float tn = (1.f + sqrtf(fmaf(4.f * tmom, tmom, 1.f))) * 0.5f;
            float ttc = (tmom - 1.f) / tn;
            tmom = tn;
            const int nxt = cur ^ 1;

            // accumulator initialized with DtY*Linv (folds the bb add)
            f4 acc[3];
#pragma unroll
            for (int rr = 0; rr < 3; ++rr)
#pragma unroll
                for (int r = 0; r < 4; ++r) acc[rr][r] = dtL[rr][r];

#pragma unroll
            for (int kc = 0; kc < KC_N; ++kc) {
                int yo = kc * 32 + g * 8;
                s8b bh = *(const s8b*)&Yh[cur][c0][yo];
                s8b bl = *(const s8b*)&Yl[cur][c0][yo];
#pragma unroll
                for (int rr = 0; rr < 3; ++rr) {
                    if (rr < ntr) {
                        acc[rr] = __builtin_amdgcn_mfma_f32_16x16x32_bf16(ahr[rr][kc], bh, acc[rr], 0, 0, 0);
                        acc[rr] = __builtin_amdgcn_mfma_f32_16x16x32_bf16(ahr[rr][kc], bl, acc[rr], 0, 0, 0);
                        acc[rr] = __builtin_amdgcn_mfma_f32_16x16x32_bf16(alr[rr][kc], bh, acc[rr], 0, 0, 0);
                    }
                }
            }
            {   // q=160 rank-1 term in f32
                float yv = yrem[cur][c0];
#pragma unroll
                for (int rr = 0; rr < 3; ++rr)
                    if (rr < ntr)
#pragma unroll
                        for (int r = 0; r < 4; ++r)
                            acc[rr][r] = fmaf(a160r[rr][r], yv, acc[rr][r]);
            }

            // epilogue: clamp soft-threshold + momentum + truncation-split y
#pragma unroll
            for (int rr = 0; rr < 3; ++rr) {
                if (rr < ntr) {
                    unsigned yb[4], rb[4];
                    float yn0 = 0.f;
#pragma unroll
                    for (int r = 0; r < 4; ++r) {
                        float bb = acc[rr][r];
                        float wl = wlam_[rr][r];
                        float cl = fminf(fmaxf(bb, -wl), wl);   // med3 clamp
                        float xn = bb - cl;                      // soft-threshold
                        float yn = fmaf(ttc, xn - x_[rr][r], xn);
                        x_[rr][r] = xn;
                        if (r == 0) yn0 = yn;
                        unsigned u = __float_as_uint(yn);
                        yb[r] = u;
                        rb[r] = __float_as_uint(yn - __uint_as_float(u & 0xFFFF0000u));
                    }
                    int rt = rt0 + rr;
                    if (rt < 10) {
                        uint2 hp, lp;
                        hp.x = __builtin_amdgcn_perm(yb[1], yb[0], 0x07060302u);
                        hp.y = __builtin_amdgcn_perm(yb[3], yb[2], 0x07060302u);
                        lp.x = __builtin_amdgcn_perm(rb[1], rb[0], 0x07060302u);
                        lp.y = __builtin_amdgcn_perm(rb[3], rb[2], 0x07060302u);
                        *(uint2*)&Yh[nxt][c0][rowb[rr]] = hp;
                        *(uint2*)&Yl[nxt][c0][rowb[rr]] = lp;
                    } else if (g == 0) {
                        yrem[nxt][c0] = yn0;   // row 160 (rows >160 are pad, y=0)
                    }
                }
            }
            __syncthreads();   // writes to nxt visible; all reads of cur complete
            cur = nxt;
        }

        if (round == 0) {
            // reweight: wlam = (1/(|x|+.01)) / colsum(1/(|x|+.01)) * NP * lamL
            float ps = 0.f;
#pragma unroll
            for (int rr = 0; rr < 3; ++rr) {
                if (rr < ntr) {
#pragma unroll
                    for (int r = 0; r < 4; ++r) {
                        if (rowb[rr] + r < NP)
                            ps += 1.f / (fabsf(x_[rr][r]) + 0.01f);
                    }
                }
            }
            ps += __shfl_xor(ps, 16);
            ps += __shfl_xor(ps, 32);
            if (lane < 16) colpart[w][lane] = ps;
            __syncthreads();
            if (tid < 16) {
                float s = colpart[0][tid] + colpart[1][tid] + colpart[2][tid] + colpart[3][tid];
                sS[tid] = (float)NP / s;
            }
            __syncthreads();
            float sc = sS[c0] * lamL;
#pragma unroll
            for (int rr = 0; rr < 3; ++rr)
#pragma unroll
                for (int r = 0; r < 4; ++r)
                    wlam_[rr][r] = (1.f / (fabsf(x_[rr][r]) + 0.01f)) * sc;
            __syncthreads();
        }
    }

    // store C (f32)
#pragma unroll
    for (int rr = 0; rr < 3; ++rr) {
        if ((rr < ntr) && cvalid) {
#pragma unroll
            for (int r = 0; r < 4; ++r) {
                int row = rowb[rr] + r;
                if (row < NP)
                    Cout[n * NPD + row * DDATA + colv] = x_[rr][r];
            }
        }
    }
}

// ---------------- R = D @ C ------------------------------------------------
__global__ void k_R(const float* __restrict__ Dw, const float* __restrict__ Cf,
                    float* __restrict__ Rout) {
    int idx = blockIdx.x * 256 + threadIdx.x;
    if (idx >= RSIZE) return;
    int n = idx / TD;
    int r = idx - n * TD;
    int t = r / DDATA;
    int d = r - t * DDATA;
    const float* xp = Cf + n * NPD + d;
    float acc = 0.f;
    for (int p = 0; p < NP; ++p) acc = fmaf(Dw[t * NP + p], xp[p * DDATA], acc);
    Rout[idx] = acc;
}

extern "C" void kernel_launch(void* const* d_in, const int* in_sizes, int n_in,
                              void* d_out, int out_size, void* d_ws, size_t ws_size,
                              hipStream_t stream) {
    const float* Y     = (const float*)d_in[0];
    const float* rho   = (const float*)d_in[1];
    const float* theta = (const float*)d_in[2];
    float* Cout = (float*)d_out;
    float* Dout = Cout + CSIZE;
    float* Rout = Dout + DSIZE;

    float* ws    = (float*)d_ws;
    float* Dw    = ws;                 // 5824
    float* Apad  = Dw + 5824;          // 26416
    float* DDt   = Apad + 26416;       // 1312
    float* scal  = DDt + 1312;         // 16
    float* dty   = scal + 16;          // CSIZE
    float* AfH_f = dty + CSIZE;        // 14080 floats (= 28160 shorts)
    float* AfL_f = AfH_f + 14080;      // 14080 floats

    k_build_D<<<(DSIZE + 255) / 256, 256, 0, stream>>>(rho, theta, Dw, Dout);
    k_ddt<<<(TSEQ * TSEQ + 255) / 256, 256, 0, stream>>>(Dw, DDt);
    k_power<<<1, 64, 0, stream>>>(DDt, scal);
    k_A<<<(NP * NPAD + 255) / 256, 256, 0, stream>>>(Dw, scal, Apad);
    k_dty<<<(CSIZE + 255) / 256, 256, 0, stream>>>(Dw, Y, dty);
    k_Afrag<<<(RT_N * KC_N * 64 + 255) / 256, 256, 0, stream>>>(Apad, (short*)AfH_f, (short*)AfL_f);

    k_fista<<<NSAMP * 4, 256, 0, stream>>>(Apad, (const s8b*)AfH_f, (const s8b*)AfL_f,
                                           dty, scal, Cout);

    k_R<<<(RSIZE + 255) / 256, 256, 0, stream>>>(Dw, Cout, Rout);
}

// Round 8
// 392.216 us; speedup vs baseline: 17.4096x; 1.0066x over previous
//
#include <hip/hip_runtime.h>
#include <math.h>

#define NPOLES 80
#define NP 161          // 2*NPOLES+1
#define NPAD 164
#define TSEQ 36
#define NSAMP 128
#define DDATA 50
#define LAMF 0.1f
#define NPD (NP*DDATA)      // 8050
#define TD (TSEQ*DDATA)     // 1800
#define CSIZE (NSAMP*NPD)   // 1030400
#define RSIZE (NSAMP*TD)    // 230400
#define DSIZE (TSEQ*NP)     // 5796

#define RT_N 11             // 176 padded rows / 16
#define KC_N 5              // k chunks of 32 (q=0..159); q=160 via rank-1
#define FRAG_CHUNK 512      // shorts per (rt,kc) fragment: 64 lanes * 8

// y LDS layout: byte = slot*256 + hl*128 + c0*8 ; slot=row/4 (0..39), dbuf stride 10240B
#define YBUF 10240

typedef __attribute__((ext_vector_type(8))) short s8b;
typedef __attribute__((ext_vector_type(4))) float f4;

struct u2x2 { uint2 a, b; };

__device__ __forceinline__ unsigned short f2b(float f) {
    unsigned u = __float_as_uint(f);
    unsigned r = (u + 0x7FFFu + ((u >> 16) & 1u)) >> 16;   // RNE to bf16
    return (unsigned short)r;
}
__device__ __forceinline__ float b2f(unsigned short h) {
    return __uint_as_float(((unsigned)h) << 16);
}

// ---------------- D matrix (clamped poles) ----------------------------------
__global__ void k_build_D(const float* __restrict__ rho, const float* __restrict__ theta,
                          float* __restrict__ Dw, float* __restrict__ Dout) {
    int idx = blockIdx.x * 256 + threadIdx.x;
    if (idx >= DSIZE) return;
    int t = idx / NP, p = idx - (idx / NP) * NP;
    float v;
    if (p == 0) {
        v = 1.f;
    } else {
        int j = (p <= NPOLES) ? (p - 1) : (p - 1 - NPOLES);
        float r  = fminf(fmaxf(rho[j],   0.8f), 1.1f);
        float th = fminf(fmaxf(theta[j], 0.1f), 3.14159265358979323846f);
        double pw  = pow((double)r, (double)t);
        double ang = (double)t * (double)th;
        v = (float)(pw * ((p <= NPOLES) ? cos(ang) : sin(ang)));
    }
    Dw[idx] = v;
    Dout[idx] = v;
}

// ---------------- DDt = D @ D^T  [36x36] ------------------------------------
__global__ void k_ddt(const float* __restrict__ Dw, float* __restrict__ DDt) {
    int idx = blockIdx.x * 256 + threadIdx.x;
    if (idx >= TSEQ * TSEQ) return;
    int i = idx / TSEQ, j = idx - (idx / TSEQ) * TSEQ;
    float acc = 0.f;
    for (int p = 0; p < NP; ++p) acc = fmaf(Dw[i * NP + p], Dw[j * NP + p], acc);
    DDt[idx] = acc;
}

// ---------------- power iteration -> scal[0]=1/L ; also momentum table ------
__global__ void k_power(const float* __restrict__ DDt, float* __restrict__ scal,
                        float* __restrict__ ttab) {
    __shared__ float sM[TSEQ * TSEQ];
    __shared__ float sv[TSEQ];
    int tid = threadIdx.x;  // 64 threads = 1 wave
    // momentum table (identical float ops to the former in-loop computation)
    if (tid == 0) {
        float t = 1.f;
        for (int k = 0; k < 100; ++k) {
            float tn = (1.f + sqrtf(fmaf(4.f * t, t, 1.f))) * 0.5f;
            ttab[k] = (t - 1.f) / tn;
            t = tn;
        }
    }
    for (int i = tid; i < TSEQ * TSEQ; i += 64) sM[i] = DDt[i];
    if (tid < TSEQ) sv[tid] = 1.f;
    __syncthreads();
    for (int it = 0; it < 150; ++it) {
        float u = 0.f;
        if (tid < TSEQ) {
            for (int q = 0; q < TSEQ; ++q) u = fmaf(sM[tid * TSEQ + q], sv[q], u);
        }
        float nn = u * u;
        for (int o = 32; o > 0; o >>= 1) nn += __shfl_down(nn, o);
        nn = __shfl(nn, 0);
        float inv = rsqrtf(nn);
        __syncthreads();
        if (tid < TSEQ) sv[tid] = u * inv;
        __syncthreads();
    }
    float rq = 0.f;
    if (tid < TSEQ) {
        float uu = 0.f;
        for (int q = 0; q < TSEQ; ++q) uu = fmaf(sM[tid * TSEQ + q], sv[q], uu);
        rq = uu * sv[tid];
    }
    for (int o = 32; o > 0; o >>= 1) rq += __shfl_down(rq, o);
    if (tid == 0) { scal[0] = 1.f / rq; scal[1] = rq; }
}

// ---------------- A = I - DtD/L, padded symmetric [q][p] --------------------
__global__ void k_A(const float* __restrict__ Dw, const float* __restrict__ scal,
                    float* __restrict__ Apad) {
    int idx = blockIdx.x * 256 + threadIdx.x;
    if (idx >= NP * NPAD) return;
    int q = idx / NPAD, p = idx - (idx / NPAD) * NPAD;
    float v = 0.f;
    if (p < NP) {
        float acc = 0.f;
        for (int t = 0; t < TSEQ; ++t) acc = fmaf(Dw[t * NP + q], Dw[t * NP + p], acc);
        v = ((p == q) ? 1.f : 0.f) - acc * scal[0];
    }
    Apad[idx] = v;
}

// ---------------- DtY[n,p,d] = sum_t D[t,p] * Y[n,t,d] ----------------------
__global__ void k_dty(const float* __restrict__ Dw, const float* __restrict__ Y,
                      float* __restrict__ dty) {
    int idx = blockIdx.x * 256 + threadIdx.x;
    if (idx >= CSIZE) return;
    int n = idx / NPD;
    int r = idx - n * NPD;
    int p = r / DDATA;
    int d = r - p * DDATA;
    const float* yp = Y + n * TD + d;
    float acc = 0.f;
    for (int t = 0; t < TSEQ; ++t) acc = fmaf(Dw[t * NP + p], yp[t * DDATA], acc);
    dty[idx] = acc;
}

// ---------------- pack A into MFMA fragment order, split bf16 hi/lo ---------
__global__ void k_Afrag(const float* __restrict__ Apad,
                        short* __restrict__ AfH, short* __restrict__ AfL) {
    int idx = blockIdx.x * 256 + threadIdx.x;
    if (idx >= RT_N * KC_N * 64) return;
    int lane = idx & 63;
    int chunk = idx >> 6;
    int kc = chunk % KC_N;
    int rt = chunk / KC_N;
    int p = rt * 16 + (lane & 15);
    int q0 = kc * 32 + (lane >> 4) * 8;
    int base = chunk * FRAG_CHUNK + lane * 8;
#pragma unroll
    for (int j = 0; j < 8; ++j) {
        int q = q0 + j;
        float v = (p < NP && q < NP) ? Apad[q * NPAD + p] : 0.f;  // A[p][q] (symmetric)
        unsigned short h = f2b(v);
        float rem = v - b2f(h);
        AfH[base + j] = (short)h;
        AfL[base + j] = (short)f2b(rem);
    }
}

// ---------------- persistent MFMA FISTA: A in regs, conflict-free y LDS -----
// block=(n, col-quarter dq: 13,13,13,11 cols). grid 512 -> 2 blocks/CU.
// 4 waves: wave w owns row-tiles rt0=w*3 (3,3,3,2), one 16-col tile.
__global__ __launch_bounds__(256, 2) void k_fista(
    const float* __restrict__ Apad,
    const s8b* __restrict__ AfH, const s8b* __restrict__ AfL,
    const float* __restrict__ dty_g, const float* __restrict__ scal,
    const float* __restrict__ ttab, float* __restrict__ Cout)
{
    __shared__ char Yb[2 * YBUF];      // slot*256 + hl*128 + c0*8 (+cur*YBUF)
    __shared__ float yremf[2][16];     // y[row 160][col] f32
    __shared__ float colpart[4][16];
    __shared__ float sS[16];

    const int tid = threadIdx.x;
    const int n  = blockIdx.x >> 2;
    const int dq = blockIdx.x & 3;
    const int w = tid >> 6;
    const int lane = tid & 63;
    const int c0 = lane & 15;
    const int g = lane >> 4;
    const int rt0 = w * 3;
    const int ntr = (w == 3) ? 2 : 3;
    const int ncol = (dq == 3) ? 11 : 13;
    const int colv = dq * 13 + c0;
    const bool cvalid = c0 < ncol;
    const float Linv = scal[0];
    const float lamL = LAMF * Linv;

    const int rdbase = (c0 << 3) + (g << 9);   // c0*8 + g*512
    const int wrbase = (c0 << 3);              // + slot*256 (+128 for lo)

    // ---- persistent A fragments in registers (one-time coalesced load) ----
    s8b ahr[3][KC_N], alr[3][KC_N];
    const s8b zer = {0, 0, 0, 0, 0, 0, 0, 0};
#pragma unroll
    for (int rr = 0; rr < 3; ++rr) {
#pragma unroll
        for (int kc = 0; kc < KC_N; ++kc) {
            if (rr < ntr) {
                int ck = (rt0 + rr) * KC_N + kc;
                ahr[rr][kc] = AfH[ck * 64 + lane];
                alr[rr][kc] = AfL[ck * 64 + lane];
            } else {
                ahr[rr][kc] = zer;
                alr[rr][kc] = zer;
            }
        }
    }

    // tile geometry + dty*Linv + A[:,160] rows (C/D layout: col=l&15, row=g*4+reg)
    int rowb[3];
    float dtL[3][4];
    f4 a160r[3];
#pragma unroll
    for (int rr = 0; rr < 3; ++rr) {
        rowb[rr] = (rt0 + rr) * 16 + g * 4;
#pragma unroll
        for (int r = 0; r < 4; ++r) {
            int row = rowb[rr] + r;
            float v = 0.f;
            if ((rr < ntr) && row < NP && cvalid)
                v = dty_g[n * NPD + row * DDATA + colv];
            dtL[rr][r] = v * Linv;
            a160r[rr][r] = ((rr < ntr) && row < NP) ? Apad[160 * NPAD + row] : 0.f;
        }
    }

    float x_[3][4], wlam_[3][4];
#pragma unroll
    for (int rr = 0; rr < 3; ++rr)
#pragma unroll
        for (int r = 0; r < 4; ++r) wlam_[rr][r] = lamL;

#pragma unroll 1
    for (int round = 0; round < 2; ++round) {
#pragma unroll
        for (int rr = 0; rr < 3; ++rr)
#pragma unroll
            for (int r = 0; r < 4; ++r) x_[rr][r] = 0.f;
        {   // zero read-buffer (index 0); write-buffer fully overwritten at it 0
            unsigned* pz = (unsigned*)Yb;
            for (int i = tid; i < YBUF / 4; i += 256) pz[i] = 0u;
            if (tid < 16) yremf[0][tid] = 0.f;
        }
        int cur = 0;
        __syncthreads();

#pragma unroll 1
        for (int it = 0; it < 100; ++it) {
            const float ttc = ttab[it];          // uniform -> scalar load
            const int nxt = cur ^ 1;
            const char* rp = Yb + cur * YBUF + rdbase;
            char* wp = Yb + nxt * YBUF + wrbase;

            // accumulator initialized with DtY*Linv (folds the bb add)
            f4 acc[3];
#pragma unroll
            for (int rr = 0; rr < 3; ++rr)
#pragma unroll
                for (int r = 0; r < 4; ++r) acc[rr][r] = dtL[rr][r];

            __builtin_amdgcn_s_setprio(1);
#pragma unroll
            for (int kc = 0; kc < KC_N; ++kc) {
                const char* p = rp + kc * 2048;
                u2x2 hh2, ll2;
                hh2.a = *(const uint2*)(p);
                hh2.b = *(const uint2*)(p + 256);
                ll2.a = *(const uint2*)(p + 128);
                ll2.b = *(const uint2*)(p + 384);
                s8b bh = __builtin_bit_cast(s8b, hh2);
                s8b bl = __builtin_bit_cast(s8b, ll2);
#pragma unroll
                for (int rr = 0; rr < 3; ++rr) {
                    if (rr < ntr) {
                        acc[rr] = __builtin_amdgcn_mfma_f32_16x16x32_bf16(ahr[rr][kc], bh, acc[rr], 0, 0, 0);
                        acc[rr] = __builtin_amdgcn_mfma_f32_16x16x32_bf16(ahr[rr][kc], bl, acc[rr], 0, 0, 0);
                        acc[rr] = __builtin_amdgcn_mfma_f32_16x16x32_bf16(alr[rr][kc], bh, acc[rr], 0, 0, 0);
                    }
                }
            }
            {   // q=160 rank-1 term in f32
                float yv = yremf[cur][c0];
#pragma unroll
                for (int rr = 0; rr < 3; ++rr)
                    if (rr < ntr)
#pragma unroll
                        for (int r = 0; r < 4; ++r)
                            acc[rr][r] = fmaf(a160r[rr][r], yv, acc[rr][r]);
            }
            __builtin_amdgcn_s_setprio(0);

            // epilogue: clamp soft-threshold + momentum + truncation-split y
#pragma unroll
            for (int rr = 0; rr < 3; ++rr) {
                if (rr < ntr) {
                    unsigned yb4[4], rb4[4];
                    float yn0 = 0.f;
#pragma unroll
                    for (int r = 0; r < 4; ++r) {
                        float bb = acc[rr][r];
                        float wl = wlam_[rr][r];
                        float cl = fminf(fmaxf(bb, -wl), wl);   // med3 clamp
                        float xn = bb - cl;                      // soft-threshold
                        float yn = fmaf(ttc, xn - x_[rr][r], xn);
                        x_[rr][r] = xn;
                        if (r == 0) yn0 = yn;
                        unsigned u = __float_as_uint(yn);
                        yb4[r] = u;
                        rb4[r] = __float_as_uint(yn - __uint_as_float(u & 0xFFFF0000u));
                    }
                    int rt = rt0 + rr;
                    if (rt < 10) {
                        uint2 hp, lp;
                        hp.x = __builtin_amdgcn_perm(yb4[1], yb4[0], 0x07060302u);
                        hp.y = __builtin_amdgcn_perm(yb4[3], yb4[2], 0x07060302u);
                        lp.x = __builtin_amdgcn_perm(rb4[1], rb4[0], 0x07060302u);
                        lp.y = __builtin_amdgcn_perm(rb4[3], rb4[2], 0x07060302u);
                        char* q = wp + (rt * 4 + g) * 256;
                        *(uint2*)(q)       = hp;
                        *(uint2*)(q + 128) = lp;
                    } else if (g == 0) {
                        yremf[nxt][c0] = yn0;   // row 160 (rows >160 are pad, y=0)
                    }
                }
            }
            __syncthreads();   // writes to nxt visible; all reads of cur complete
            cur = nxt;
        }

        if (round == 0) {
            // reweight: wlam = (1/(|x|+.01)) / colsum(1/(|x|+.01)) * NP * lamL
            float ps = 0.f;
#pragma unroll
            for (int rr = 0; rr < 3; ++rr) {
                if (rr < ntr) {
#pragma unroll
                    for (int r = 0; r < 4; ++r) {
                        if (rowb[rr] + r < NP)
                            ps += 1.f / (fabsf(x_[rr][r]) + 0.01f);
                    }
                }
            }
            ps += __shfl_xor(ps, 16);
            ps += __shfl_xor(ps, 32);
            if (lane < 16) colpart[w][lane] = ps;
            __syncthreads();
            if (tid < 16) {
                float s = colpart[0][tid] + colpart[1][tid] + colpart[2][tid] + colpart[3][tid];
                sS[tid] = (float)NP / s;
            }
            __syncthreads();
            float sc = sS[c0] * lamL;
#pragma unroll
            for (int rr = 0; rr < 3; ++rr)
#pragma unroll
                for (int r = 0; r < 4; ++r)
                    wlam_[rr][r] = (1.f / (fabsf(x_[rr][r]) + 0.01f)) * sc;
            __syncthreads();
        }
    }

    // store C (f32)
#pragma unroll
    for (int rr = 0; rr < 3; ++rr) {
        if ((rr < ntr) && cvalid) {
#pragma unroll
            for (int r = 0; r < 4; ++r) {
                int row = rowb[rr] + r;
                if (row < NP)
                    Cout[n * NPD + row * DDATA + colv] = x_[rr][r];
            }
        }
    }
}

// ---------------- R = D @ C ------------------------------------------------
__global__ void k_R(const float* __restrict__ Dw, const float* __restrict__ Cf,
                    float* __restrict__ Rout) {
    int idx = blockIdx.x * 256 + threadIdx.x;
    if (idx >= RSIZE) return;
    int n = idx / TD;
    int r = idx - n * TD;
    int t = r / DDATA;
    int d = r - t * DDATA;
    const float* xp = Cf + n * NPD + d;
    float acc = 0.f;
    for (int p = 0; p < NP; ++p) acc = fmaf(Dw[t * NP + p], xp[p * DDATA], acc);
    Rout[idx] = acc;
}

extern "C" void kernel_launch(void* const* d_in, const int* in_sizes, int n_in,
                              void* d_out, int out_size, void* d_ws, size_t ws_size,
                              hipStream_t stream) {
    const float* Y     = (const float*)d_in[0];
    const float* rho   = (const float*)d_in[1];
    const float* theta = (const float*)d_in[2];
    float* Cout = (float*)d_out;
    float* Dout = Cout + CSIZE;
    float* Rout = Dout + DSIZE;

    float* ws    = (float*)d_ws;
    float* Dw    = ws;                 // 5824
    float* Apad  = Dw + 5824;          // 26416
    float* DDt   = Apad + 26416;       // 1312
    float* scal  = DDt + 1312;         // 16
    float* ttabd = scal + 16;          // 112
    float* dty   = ttabd + 112;        // CSIZE
    float* AfH_f = dty + CSIZE;        // 14080 floats (= 28160 shorts)
    float* AfL_f = AfH_f + 14080;      // 14080 floats

    k_build_D<<<(DSIZE + 255) / 256, 256, 0, stream>>>(rho, theta, Dw, Dout);
    k_ddt<<<(TSEQ * TSEQ + 255) / 256, 256, 0, stream>>>(Dw, DDt);
    k_power<<<1, 64, 0, stream>>>(DDt, scal, ttabd);
    k_A<<<(NP * NPAD + 255) / 256, 256, 0, stream>>>(Dw, scal, Apad);
    k_dty<<<(CSIZE + 255) / 256, 256, 0, stream>>>(Dw, Y, dty);
    k_Afrag<<<(RT_N * KC_N * 64 + 255) / 256, 256, 0, stream>>>(Apad, (short*)AfH_f, (short*)AfL_f);

    k_fista<<<NSAMP * 4, 256, 0, stream>>>(Apad, (const s8b*)AfH_f, (const s8b*)AfL_f,
                                           dty, scal, ttabd, Cout);

    k_R<<<(RSIZE + 255) / 256, 256, 0, stream>>>(Dw, Cout, Rout);
}